// Round 1
// baseline (590.670 us; speedup 1.0000x reference)
//
#include <hip/hip_runtime.h>
#include <math.h>

#define FEAT 128
#define NCLS 40
#define BN_EPS 1e-5f

// ---------------- graph prep ----------------

__global__ void k_hist(const int* __restrict__ dst, int* __restrict__ cnt, int E) {
    int e = blockIdx.x * 256 + threadIdx.x;
    if (e < E) atomicAdd(&cnt[dst[e]], 1);
}

__global__ void k_scan_a(const int* __restrict__ cnt, int* __restrict__ bsum, int n) {
    int t = threadIdx.x;
    int idx = blockIdx.x * 512 + t * 2;
    int v = 0;
    if (idx < n) v += cnt[idx];
    if (idx + 1 < n) v += cnt[idx + 1];
    for (int d = 1; d < 64; d <<= 1) v += __shfl_xor(v, d, 64);
    __shared__ int ws[4];
    int lane = t & 63, w = t >> 6;
    if (lane == 0) ws[w] = v;
    __syncthreads();
    if (t == 0) bsum[blockIdx.x] = ws[0] + ws[1] + ws[2] + ws[3];
}

__global__ void k_scan_b(const int* __restrict__ bsum, int* __restrict__ boff,
                         int* __restrict__ row_off, int nb, int n) {
    if (threadIdx.x == 0) {
        int run = 0;
        for (int i = 0; i < nb; ++i) { boff[i] = run; run += bsum[i]; }
        row_off[n] = run;
    }
}

__global__ void k_scan_c(const int* __restrict__ cnt, const int* __restrict__ boff,
                         int* __restrict__ row_off, int* __restrict__ cursor,
                         float* __restrict__ dinv, int n) {
    int t = threadIdx.x;
    int idx = blockIdx.x * 512 + t * 2;
    int v0 = (idx < n) ? cnt[idx] : 0;
    int v1 = (idx + 1 < n) ? cnt[idx + 1] : 0;
    int s = v0 + v1;
    int lane = t & 63, w = t >> 6;
    int incl = s;
    for (int d = 1; d < 64; d <<= 1) {
        int o = __shfl_up(incl, d, 64);
        if (lane >= d) incl += o;
    }
    __shared__ int wsum[4];
    if (lane == 63) wsum[w] = incl;
    __syncthreads();
    int wpre = 0;
    for (int i = 0; i < w; ++i) wpre += wsum[i];
    int base = boff[blockIdx.x] + wpre + incl - s;
    if (idx < n) {
        row_off[idx] = base; cursor[idx] = base;
        dinv[idx] = rsqrtf((float)(v0 + 1));
    }
    if (idx + 1 < n) {
        row_off[idx + 1] = base + v0; cursor[idx + 1] = base + v0;
        dinv[idx + 1] = rsqrtf((float)(v1 + 1));
    }
}

__global__ void k_fill(const int* __restrict__ src, const int* __restrict__ dst,
                       int* __restrict__ cursor, int* __restrict__ col, int E) {
    int e = blockIdx.x * 256 + threadIdx.x;
    if (e < E) {
        int p = atomicAdd(&cursor[dst[e]], 1);
        col[p] = src[e];
    }
}

// ---------------- GEMM 128x128 (optional fused BN+ReLU on input) ----------------
// Block: 64 rows x 128 cols, 256 threads, thread = 4 rows x 8 cols.

__global__ __launch_bounds__(256) void k_gemm128(
    const float* __restrict__ X, const float* __restrict__ W,
    const float* __restrict__ scale, const float* __restrict__ shift,
    float* __restrict__ Y, int M)
{
    __shared__ float Wsc[32 * 128];   // 16 KB: W rows k0..k0+31
    __shared__ float Xs[32 * 68];     // transposed tile: Xs[kk][row], pad 68

    int t = threadIdx.x;
    int row0 = blockIdx.x * 64;
    int tx = t & 15, ty = t >> 4;

    float acc[4][8];
#pragma unroll
    for (int r = 0; r < 4; ++r)
#pragma unroll
        for (int c = 0; c < 8; ++c) acc[r][c] = 0.f;

    for (int k0 = 0; k0 < 128; k0 += 32) {
        __syncthreads();
        // stage W chunk (32x128 = 1024 float4)
        {
            const float4* W4 = (const float4*)(W + k0 * 128);
            float4* Ws4 = (float4*)Wsc;
#pragma unroll
            for (int i = 0; i < 4; ++i) Ws4[t + i * 256] = W4[t + i * 256];
        }
        // stage X tile (64 rows x 32 k), transposed, with optional BN+ReLU
        {
            int rr = t >> 3;
            int kc = (t & 7) * 4;
#pragma unroll
            for (int p = 0; p < 2; ++p) {
                int r = rr + p * 32;
                int grow = row0 + r;
                float4 v = make_float4(0.f, 0.f, 0.f, 0.f);
                if (grow < M) v = *(const float4*)(X + (size_t)grow * 128 + k0 + kc);
                if (scale) {
                    float4 sc = *(const float4*)(scale + k0 + kc);
                    float4 sh = *(const float4*)(shift + k0 + kc);
                    v.x = fmaxf(fmaf(v.x, sc.x, sh.x), 0.f);
                    v.y = fmaxf(fmaf(v.y, sc.y, sh.y), 0.f);
                    v.z = fmaxf(fmaf(v.z, sc.z, sh.z), 0.f);
                    v.w = fmaxf(fmaf(v.w, sc.w, sh.w), 0.f);
                }
                Xs[(kc + 0) * 68 + r] = v.x;
                Xs[(kc + 1) * 68 + r] = v.y;
                Xs[(kc + 2) * 68 + r] = v.z;
                Xs[(kc + 3) * 68 + r] = v.w;
            }
        }
        __syncthreads();
#pragma unroll 8
        for (int kk = 0; kk < 32; ++kk) {
            const float4 xv = *(const float4*)&Xs[kk * 68 + ty * 4];
            const float4 wa = *(const float4*)&Wsc[kk * 128 + tx * 8];
            const float4 wb = *(const float4*)&Wsc[kk * 128 + tx * 8 + 4];
            const float xr[4] = {xv.x, xv.y, xv.z, xv.w};
            const float wc[8] = {wa.x, wa.y, wa.z, wa.w, wb.x, wb.y, wb.z, wb.w};
#pragma unroll
            for (int r = 0; r < 4; ++r)
#pragma unroll
                for (int c = 0; c < 8; ++c)
                    acc[r][c] = fmaf(xr[r], wc[c], acc[r][c]);
        }
    }

#pragma unroll
    for (int r = 0; r < 4; ++r) {
        int grow = row0 + ty * 4 + r;
        if (grow < M) {
            float4 o0 = make_float4(acc[r][0], acc[r][1], acc[r][2], acc[r][3]);
            float4 o1 = make_float4(acc[r][4], acc[r][5], acc[r][6], acc[r][7]);
            *(float4*)(Y + (size_t)grow * 128 + tx * 8) = o0;
            *(float4*)(Y + (size_t)grow * 128 + tx * 8 + 4) = o1;
        }
    }
}

// ---------------- GEMM 128->40 (fused BN+ReLU on input) ----------------
// Block: 256 rows x 40 cols, 256 threads, thread = 4 rows x 10 cols.

__global__ __launch_bounds__(256) void k_gemm40(
    const float* __restrict__ X, const float* __restrict__ W,
    const float* __restrict__ scale, const float* __restrict__ shift,
    float* __restrict__ Y, int M)
{
    __shared__ float Ws[128 * 40];    // 20 KB, staged once
    __shared__ float Xs[32 * 260];    // transposed: Xs[kk][row], pad 260

    int t = threadIdx.x;
    int row0 = blockIdx.x * 256;
    int tx = t & 3, ty = t >> 2;

    {
        const float4* W4 = (const float4*)W;
        float4* Ws4 = (float4*)Ws;
#pragma unroll
        for (int i = 0; i < 5; ++i) Ws4[t + i * 256] = W4[t + i * 256];
    }

    float acc[4][10];
#pragma unroll
    for (int r = 0; r < 4; ++r)
#pragma unroll
        for (int c = 0; c < 10; ++c) acc[r][c] = 0.f;

    for (int k0 = 0; k0 < 128; k0 += 32) {
        __syncthreads();
        {
            int rr = t >> 3;
            int kc = (t & 7) * 4;
            float4 sc = *(const float4*)(scale + k0 + kc);
            float4 sh = *(const float4*)(shift + k0 + kc);
#pragma unroll
            for (int p = 0; p < 8; ++p) {
                int r = rr + p * 32;
                int grow = row0 + r;
                float4 v = make_float4(0.f, 0.f, 0.f, 0.f);
                if (grow < M) v = *(const float4*)(X + (size_t)grow * 128 + k0 + kc);
                v.x = fmaxf(fmaf(v.x, sc.x, sh.x), 0.f);
                v.y = fmaxf(fmaf(v.y, sc.y, sh.y), 0.f);
                v.z = fmaxf(fmaf(v.z, sc.z, sh.z), 0.f);
                v.w = fmaxf(fmaf(v.w, sc.w, sh.w), 0.f);
                Xs[(kc + 0) * 260 + r] = v.x;
                Xs[(kc + 1) * 260 + r] = v.y;
                Xs[(kc + 2) * 260 + r] = v.z;
                Xs[(kc + 3) * 260 + r] = v.w;
            }
        }
        __syncthreads();
#pragma unroll 8
        for (int kk = 0; kk < 32; ++kk) {
            const float4 xv = *(const float4*)&Xs[kk * 260 + ty * 4];
            const float xr[4] = {xv.x, xv.y, xv.z, xv.w};
            float wc[10];
#pragma unroll
            for (int c = 0; c < 5; ++c) {
                float2 w2 = *(const float2*)&Ws[(k0 + kk) * 40 + tx * 10 + c * 2];
                wc[c * 2] = w2.x; wc[c * 2 + 1] = w2.y;
            }
#pragma unroll
            for (int r = 0; r < 4; ++r)
#pragma unroll
                for (int c = 0; c < 10; ++c)
                    acc[r][c] = fmaf(xr[r], wc[c], acc[r][c]);
        }
    }

#pragma unroll
    for (int r = 0; r < 4; ++r) {
        int grow = row0 + ty * 4 + r;
        if (grow < M) {
#pragma unroll
            for (int c = 0; c < 5; ++c) {
                float2 o; o.x = acc[r][c * 2]; o.y = acc[r][c * 2 + 1];
                *(float2*)(Y + (size_t)grow * 40 + tx * 10 + c * 2) = o;
            }
        }
    }
}

// ---------------- aggregation: out[i] = dinv[i]*(sum_e dinv[s]*t[s] + dinv[i]*t[i]) + b ----

__global__ __launch_bounds__(256) void k_agg128(
    const float* __restrict__ t, const int* __restrict__ roff,
    const int* __restrict__ col, const float* __restrict__ dinv,
    const float* __restrict__ bias, float* __restrict__ out, int n)
{
    int i = blockIdx.x * 4 + (threadIdx.x >> 6);
    if (i >= n) return;
    int lane = threadIdx.x & 63;
    int beg = roff[i], end = roff[i + 1];
    float di = dinv[i];
    float2 sv = ((const float2*)(t + (size_t)i * 128))[lane];
    float ax = di * sv.x, ay = di * sv.y;
    int j = beg;
    for (; j + 1 < end; j += 2) {
        int s0 = col[j], s1 = col[j + 1];
        float w0 = dinv[s0], w1 = dinv[s1];
        float2 v0 = ((const float2*)(t + (size_t)s0 * 128))[lane];
        float2 v1 = ((const float2*)(t + (size_t)s1 * 128))[lane];
        ax = fmaf(w0, v0.x, ax); ay = fmaf(w0, v0.y, ay);
        ax = fmaf(w1, v1.x, ax); ay = fmaf(w1, v1.y, ay);
    }
    if (j < end) {
        int s0 = col[j];
        float w0 = dinv[s0];
        float2 v0 = ((const float2*)(t + (size_t)s0 * 128))[lane];
        ax = fmaf(w0, v0.x, ax); ay = fmaf(w0, v0.y, ay);
    }
    float2 bb = ((const float2*)bias)[lane];
    float2 o; o.x = fmaf(di, ax, bb.x); o.y = fmaf(di, ay, bb.y);
    ((float2*)(out + (size_t)i * 128))[lane] = o;
}

// ---------------- BN stats over node axis ----------------

__global__ __launch_bounds__(256) void k_bnstats(const float* __restrict__ a,
                                                 float* __restrict__ sums, int n) {
    int f = threadIdx.x & 127;
    int g = threadIdx.x >> 7;
    float s = 0.f, q = 0.f;
    for (int i = blockIdx.x * 2 + g; i < n; i += gridDim.x * 2) {
        float v = a[(size_t)i * 128 + f];
        s += v; q = fmaf(v, v, q);
    }
    __shared__ float ls[256], lq[256];
    ls[threadIdx.x] = s; lq[threadIdx.x] = q;
    __syncthreads();
    if (g == 0) {
        atomicAdd(&sums[f], s + ls[128 + f]);
        atomicAdd(&sums[128 + f], q + lq[128 + f]);
    }
}

__global__ void k_bnfinal(const float* __restrict__ sums, const float* __restrict__ gamma,
                          const float* __restrict__ beta, float* __restrict__ scale,
                          float* __restrict__ shift, int n) {
    int f = threadIdx.x;
    float inv_n = 1.f / (float)n;
    float mu = sums[f] * inv_n;
    float var = sums[128 + f] * inv_n - mu * mu;
    float rs = rsqrtf(var + BN_EPS);
    float sc = gamma[f] * rs;
    scale[f] = sc;
    shift[f] = beta[f] - mu * sc;
}

// ---------------- final: 40-wide aggregation + bias + log_softmax ----------------

__global__ __launch_bounds__(256) void k_agg40(
    const float* __restrict__ t, const int* __restrict__ roff,
    const int* __restrict__ col, const float* __restrict__ dinv,
    const float* __restrict__ bias, float* __restrict__ out, int n)
{
    int i = blockIdx.x * 4 + (threadIdx.x >> 6);
    if (i >= n) return;
    int lane = threadIdx.x & 63;
    bool act = lane < NCLS;
    int beg = roff[i], end = roff[i + 1];
    float di = dinv[i];
    float a = act ? di * t[(size_t)i * NCLS + lane] : 0.f;
    int j = beg;
    for (; j + 1 < end; j += 2) {
        int s0 = col[j], s1 = col[j + 1];
        float w0 = dinv[s0], w1 = dinv[s1];
        float u0 = act ? t[(size_t)s0 * NCLS + lane] : 0.f;
        float u1 = act ? t[(size_t)s1 * NCLS + lane] : 0.f;
        a = fmaf(w0, u0, a);
        a = fmaf(w1, u1, a);
    }
    if (j < end) {
        int s0 = col[j];
        float w0 = dinv[s0];
        float u0 = act ? t[(size_t)s0 * NCLS + lane] : 0.f;
        a = fmaf(w0, u0, a);
    }
    float v = act ? (fmaf(di, a, bias[lane])) : -INFINITY;
    float m = v;
    for (int d = 32; d > 0; d >>= 1) m = fmaxf(m, __shfl_xor(m, d, 64));
    float e = act ? expf(v - m) : 0.f;
    float ssum = e;
    for (int d = 32; d > 0; d >>= 1) ssum += __shfl_xor(ssum, d, 64);
    if (act) out[(size_t)i * NCLS + lane] = v - m - logf(ssum);
}

// ---------------- launch ----------------

extern "C" void kernel_launch(void* const* d_in, const int* in_sizes, int n_in,
                              void* d_out, int out_size, void* d_ws, size_t ws_size,
                              hipStream_t stream) {
    const float* features = (const float*)d_in[0];
    const int* edge_index = (const int*)d_in[1];
    const float* W1 = (const float*)d_in[2];
    const float* b1 = (const float*)d_in[3];
    const float* gamma1 = (const float*)d_in[4];
    const float* beta1 = (const float*)d_in[5];
    const float* W2 = (const float*)d_in[6];
    const float* b2 = (const float*)d_in[7];
    const float* gamma2 = (const float*)d_in[8];
    const float* beta2 = (const float*)d_in[9];
    const float* W3 = (const float*)d_in[10];
    const float* b3 = (const float*)d_in[11];
    float* out = (float*)d_out;

    int n = in_sizes[0] / FEAT;
    int E = in_sizes[1] / 2;

    char* p = (char*)d_ws;
    auto alloc = [&](size_t bytes) -> void* {
        void* r = (void*)p;
        p += (bytes + 255) & ~(size_t)255;
        return r;
    };
    int* cnt     = (int*)alloc((size_t)n * 4);
    int* row_off = (int*)alloc((size_t)(n + 1) * 4);
    int* cursor  = (int*)alloc((size_t)n * 4);
    int* colb    = (int*)alloc((size_t)E * 4);
    int* bsum    = (int*)alloc(1024);
    int* boff    = (int*)alloc(1024);
    float* dinv  = (float*)alloc((size_t)n * 4);
    float* sums  = (float*)alloc(256 * 4);
    float* scale1 = (float*)alloc(128 * 4);
    float* shift1 = (float*)alloc(128 * 4);
    float* scale2 = (float*)alloc(128 * 4);
    float* shift2 = (float*)alloc(128 * 4);
    float* bufA  = (float*)alloc((size_t)n * 128 * 4);
    float* bufB  = (float*)alloc((size_t)n * 128 * 4);

    const int* e_src = edge_index;
    const int* e_dst = edge_index + E;

    hipMemsetAsync(cnt, 0, (size_t)n * 4, stream);
    k_hist<<<(E + 255) / 256, 256, 0, stream>>>(e_dst, cnt, E);
    int nb = (n + 511) / 512;
    k_scan_a<<<nb, 256, 0, stream>>>(cnt, bsum, n);
    k_scan_b<<<1, 64, 0, stream>>>(bsum, boff, row_off, nb, n);
    k_scan_c<<<nb, 256, 0, stream>>>(cnt, boff, row_off, cursor, dinv, n);
    k_fill<<<(E + 255) / 256, 256, 0, stream>>>(e_src, e_dst, cursor, colb, E);

    int gb64 = (n + 63) / 64;
    int gb4 = (n + 3) / 4;

    // layer 1
    k_gemm128<<<gb64, 256, 0, stream>>>(features, W1, nullptr, nullptr, bufA, n);
    k_agg128<<<gb4, 256, 0, stream>>>(bufA, row_off, colb, dinv, b1, bufB, n);
    hipMemsetAsync(sums, 0, 256 * 4, stream);
    k_bnstats<<<128, 256, 0, stream>>>(bufB, sums, n);
    k_bnfinal<<<1, 128, 0, stream>>>(sums, gamma1, beta1, scale1, shift1, n);

    // layer 2 (BN1+ReLU fused into GEMM2 input)
    k_gemm128<<<gb64, 256, 0, stream>>>(bufB, W2, scale1, shift1, bufA, n);
    k_agg128<<<gb4, 256, 0, stream>>>(bufA, row_off, colb, dinv, b2, bufB, n);
    hipMemsetAsync(sums, 0, 256 * 4, stream);
    k_bnstats<<<128, 256, 0, stream>>>(bufB, sums, n);
    k_bnfinal<<<1, 128, 0, stream>>>(sums, gamma2, beta2, scale2, shift2, n);

    // layer 3: transform first (aggregation commutes with the linear map), then 40-wide agg
    k_gemm40<<<(n + 255) / 256, 256, 0, stream>>>(bufB, W3, scale2, shift2, bufA, n);
    k_agg40<<<gb4, 256, 0, stream>>>(bufA, row_off, colb, dinv, b3, out, n);
}

// Round 2
// 518.893 us; speedup vs baseline: 1.1383x; 1.1383x over previous
//
#include <hip/hip_runtime.h>
#include <math.h>

#define FEAT 128
#define NCLS 40
#define BN_EPS 1e-5f

typedef unsigned short u16;
typedef unsigned int u32;

// bf16 helpers (RNE pack, exact unpack)
__device__ inline u32 f2b2(float a, float b) {
    u32 ua = __float_as_uint(a), ub = __float_as_uint(b);
    ua = (ua + 0x7fffu + ((ua >> 16) & 1u)) >> 16;
    ub = (ub + 0x7fffu + ((ub >> 16) & 1u)) >> 16;
    return ua | (ub << 16);
}
__device__ inline float b2f(u16 u) { return __uint_as_float((u32)u << 16); }
__device__ inline float4 b4f(ushort4 u) {
    return make_float4(b2f(u.x), b2f(u.y), b2f(u.z), b2f(u.w));
}

// ---------------- graph prep ----------------

__global__ void k_hist(const int* __restrict__ dst, int* __restrict__ cnt, int E) {
    int e = blockIdx.x * 256 + threadIdx.x;
    if (e < E) atomicAdd(&cnt[dst[e]], 1);
}

__global__ void k_scan_a(const int* __restrict__ cnt, int* __restrict__ bsum, int n) {
    int t = threadIdx.x;
    int idx = blockIdx.x * 512 + t * 2;
    int v = 0;
    if (idx < n) v += cnt[idx];
    if (idx + 1 < n) v += cnt[idx + 1];
    for (int d = 1; d < 64; d <<= 1) v += __shfl_xor(v, d, 64);
    __shared__ int ws[4];
    int lane = t & 63, w = t >> 6;
    if (lane == 0) ws[w] = v;
    __syncthreads();
    if (t == 0) bsum[blockIdx.x] = ws[0] + ws[1] + ws[2] + ws[3];
}

__global__ void k_scan_b(const int* __restrict__ bsum, int* __restrict__ boff,
                         int* __restrict__ row_off, int nb, int n) {
    if (threadIdx.x == 0) {
        int run = 0;
        for (int i = 0; i < nb; ++i) { boff[i] = run; run += bsum[i]; }
        row_off[n] = run;
    }
}

__global__ void k_scan_c(const int* __restrict__ cnt, const int* __restrict__ boff,
                         int* __restrict__ row_off, int* __restrict__ cursor,
                         float* __restrict__ dinv, int n) {
    int t = threadIdx.x;
    int idx = blockIdx.x * 512 + t * 2;
    int v0 = (idx < n) ? cnt[idx] : 0;
    int v1 = (idx + 1 < n) ? cnt[idx + 1] : 0;
    int s = v0 + v1;
    int lane = t & 63, w = t >> 6;
    int incl = s;
    for (int d = 1; d < 64; d <<= 1) {
        int o = __shfl_up(incl, d, 64);
        if (lane >= d) incl += o;
    }
    __shared__ int wsum[4];
    if (lane == 63) wsum[w] = incl;
    __syncthreads();
    int wpre = 0;
    for (int i = 0; i < w; ++i) wpre += wsum[i];
    int base = boff[blockIdx.x] + wpre + incl - s;
    if (idx < n) {
        row_off[idx] = base; cursor[idx] = base;
        dinv[idx] = rsqrtf((float)(v0 + 1));
    }
    if (idx + 1 < n) {
        row_off[idx + 1] = base + v0; cursor[idx + 1] = base + v0;
        dinv[idx + 1] = rsqrtf((float)(v1 + 1));
    }
}

// fill CSR columns AND per-edge weight w = dinv[src] (kills dependent gather in agg loop)
__global__ void k_fill(const int* __restrict__ src, const int* __restrict__ dst,
                       int* __restrict__ cursor, int* __restrict__ col,
                       const float* __restrict__ dinv, float* __restrict__ wsrc, int E) {
    int e = blockIdx.x * 256 + threadIdx.x;
    if (e < E) {
        int s = src[e];
        int p = atomicAdd(&cursor[dst[e]], 1);
        col[p] = s;
        wsrc[p] = dinv[s];
    }
}

// ---------------- GEMM 128x128, fp32 compute, bf16 output ----------------
// Block: 64 rows x 128 cols, 256 threads, thread = 4 rows x 8 cols.

__global__ __launch_bounds__(256) void k_gemm128(
    const float* __restrict__ X, const float* __restrict__ W,
    const float* __restrict__ scale, const float* __restrict__ shift,
    u16* __restrict__ Y, int M)
{
    __shared__ float Wsc[32 * 128];
    __shared__ float Xs[32 * 68];

    int t = threadIdx.x;
    int row0 = blockIdx.x * 64;
    int tx = t & 15, ty = t >> 4;

    float acc[4][8];
#pragma unroll
    for (int r = 0; r < 4; ++r)
#pragma unroll
        for (int c = 0; c < 8; ++c) acc[r][c] = 0.f;

    for (int k0 = 0; k0 < 128; k0 += 32) {
        __syncthreads();
        {
            const float4* W4 = (const float4*)(W + k0 * 128);
            float4* Ws4 = (float4*)Wsc;
#pragma unroll
            for (int i = 0; i < 4; ++i) Ws4[t + i * 256] = W4[t + i * 256];
        }
        {
            int rr = t >> 3;
            int kc = (t & 7) * 4;
#pragma unroll
            for (int p = 0; p < 2; ++p) {
                int r = rr + p * 32;
                int grow = row0 + r;
                float4 v = make_float4(0.f, 0.f, 0.f, 0.f);
                if (grow < M) v = *(const float4*)(X + (size_t)grow * 128 + k0 + kc);
                if (scale) {
                    float4 sc = *(const float4*)(scale + k0 + kc);
                    float4 sh = *(const float4*)(shift + k0 + kc);
                    v.x = fmaxf(fmaf(v.x, sc.x, sh.x), 0.f);
                    v.y = fmaxf(fmaf(v.y, sc.y, sh.y), 0.f);
                    v.z = fmaxf(fmaf(v.z, sc.z, sh.z), 0.f);
                    v.w = fmaxf(fmaf(v.w, sc.w, sh.w), 0.f);
                }
                Xs[(kc + 0) * 68 + r] = v.x;
                Xs[(kc + 1) * 68 + r] = v.y;
                Xs[(kc + 2) * 68 + r] = v.z;
                Xs[(kc + 3) * 68 + r] = v.w;
            }
        }
        __syncthreads();
#pragma unroll 8
        for (int kk = 0; kk < 32; ++kk) {
            const float4 xv = *(const float4*)&Xs[kk * 68 + ty * 4];
            const float4 wa = *(const float4*)&Wsc[kk * 128 + tx * 8];
            const float4 wb = *(const float4*)&Wsc[kk * 128 + tx * 8 + 4];
            const float xr[4] = {xv.x, xv.y, xv.z, xv.w};
            const float wc[8] = {wa.x, wa.y, wa.z, wa.w, wb.x, wb.y, wb.z, wb.w};
#pragma unroll
            for (int r = 0; r < 4; ++r)
#pragma unroll
                for (int c = 0; c < 8; ++c)
                    acc[r][c] = fmaf(xr[r], wc[c], acc[r][c]);
        }
    }

#pragma unroll
    for (int r = 0; r < 4; ++r) {
        int grow = row0 + ty * 4 + r;
        if (grow < M) {
            uint4 o;
            o.x = f2b2(acc[r][0], acc[r][1]);
            o.y = f2b2(acc[r][2], acc[r][3]);
            o.z = f2b2(acc[r][4], acc[r][5]);
            o.w = f2b2(acc[r][6], acc[r][7]);
            *(uint4*)(Y + (size_t)grow * 128 + tx * 8) = o;   // 16B aligned
        }
    }
}

// ---------------- GEMM 128->40 (fused BN+ReLU on input), bf16 output ----------------

__global__ __launch_bounds__(256) void k_gemm40(
    const float* __restrict__ X, const float* __restrict__ W,
    const float* __restrict__ scale, const float* __restrict__ shift,
    u16* __restrict__ Y, int M)
{
    __shared__ float Ws[128 * 40];
    __shared__ float Xs[32 * 260];

    int t = threadIdx.x;
    int row0 = blockIdx.x * 256;
    int tx = t & 3, ty = t >> 2;

    {
        const float4* W4 = (const float4*)W;
        float4* Ws4 = (float4*)Ws;
#pragma unroll
        for (int i = 0; i < 5; ++i) Ws4[t + i * 256] = W4[t + i * 256];
    }

    float acc[4][10];
#pragma unroll
    for (int r = 0; r < 4; ++r)
#pragma unroll
        for (int c = 0; c < 10; ++c) acc[r][c] = 0.f;

    for (int k0 = 0; k0 < 128; k0 += 32) {
        __syncthreads();
        {
            int rr = t >> 3;
            int kc = (t & 7) * 4;
            float4 sc = *(const float4*)(scale + k0 + kc);
            float4 sh = *(const float4*)(shift + k0 + kc);
#pragma unroll
            for (int p = 0; p < 8; ++p) {
                int r = rr + p * 32;
                int grow = row0 + r;
                float4 v = make_float4(0.f, 0.f, 0.f, 0.f);
                if (grow < M) v = *(const float4*)(X + (size_t)grow * 128 + k0 + kc);
                v.x = fmaxf(fmaf(v.x, sc.x, sh.x), 0.f);
                v.y = fmaxf(fmaf(v.y, sc.y, sh.y), 0.f);
                v.z = fmaxf(fmaf(v.z, sc.z, sh.z), 0.f);
                v.w = fmaxf(fmaf(v.w, sc.w, sh.w), 0.f);
                Xs[(kc + 0) * 260 + r] = v.x;
                Xs[(kc + 1) * 260 + r] = v.y;
                Xs[(kc + 2) * 260 + r] = v.z;
                Xs[(kc + 3) * 260 + r] = v.w;
            }
        }
        __syncthreads();
#pragma unroll 8
        for (int kk = 0; kk < 32; ++kk) {
            const float4 xv = *(const float4*)&Xs[kk * 260 + ty * 4];
            const float xr[4] = {xv.x, xv.y, xv.z, xv.w};
            float wc[10];
#pragma unroll
            for (int c = 0; c < 5; ++c) {
                float2 w2 = *(const float2*)&Ws[(k0 + kk) * 40 + tx * 10 + c * 2];
                wc[c * 2] = w2.x; wc[c * 2 + 1] = w2.y;
            }
#pragma unroll
            for (int r = 0; r < 4; ++r)
#pragma unroll
                for (int c = 0; c < 10; ++c)
                    acc[r][c] = fmaf(xr[r], wc[c], acc[r][c]);
        }
    }

#pragma unroll
    for (int r = 0; r < 4; ++r) {
        int grow = row0 + ty * 4 + r;
        if (grow < M) {
            u32* yp = (u32*)(Y + (size_t)grow * 40 + tx * 10);  // 4B aligned
#pragma unroll
            for (int c = 0; c < 5; ++c)
                yp[c] = f2b2(acc[r][c * 2], acc[r][c * 2 + 1]);
        }
    }
}

// ---------------- aggregation (bf16 source, fp32 accum/out) ----------------
// out[i] = dinv[i]*(sum_e w_e*t[s_e] + dinv[i]*t[i]) + b
// 32 lanes per node (ushort4 = 4 bf16 = 8B/lane), 2 nodes per wave, unroll x4.

__global__ __launch_bounds__(256) void k_agg128(
    const u16* __restrict__ t, const int* __restrict__ roff,
    const int* __restrict__ col, const float* __restrict__ wsrc,
    const float* __restrict__ dinv, const float* __restrict__ bias,
    float* __restrict__ out, int n)
{
    int i = blockIdx.x * 8 + (threadIdx.x >> 5);
    if (i >= n) return;
    int lane = threadIdx.x & 31;
    int beg = roff[i], end = roff[i + 1];
    float di = dinv[i];

    ushort4 sv = ((const ushort4*)(t + (size_t)i * 128))[lane];
    float4 s4 = b4f(sv);
    float4 a = make_float4(di * s4.x, di * s4.y, di * s4.z, di * s4.w);

    int j = beg;
    for (; j + 3 < end; j += 4) {
        int s0 = col[j], s1 = col[j + 1], s2 = col[j + 2], s3 = col[j + 3];
        float w0 = wsrc[j], w1 = wsrc[j + 1], w2 = wsrc[j + 2], w3 = wsrc[j + 3];
        float4 v0 = b4f(((const ushort4*)(t + (size_t)s0 * 128))[lane]);
        float4 v1 = b4f(((const ushort4*)(t + (size_t)s1 * 128))[lane]);
        float4 v2 = b4f(((const ushort4*)(t + (size_t)s2 * 128))[lane]);
        float4 v3 = b4f(((const ushort4*)(t + (size_t)s3 * 128))[lane]);
        a.x = fmaf(w0, v0.x, a.x); a.y = fmaf(w0, v0.y, a.y);
        a.z = fmaf(w0, v0.z, a.z); a.w = fmaf(w0, v0.w, a.w);
        a.x = fmaf(w1, v1.x, a.x); a.y = fmaf(w1, v1.y, a.y);
        a.z = fmaf(w1, v1.z, a.z); a.w = fmaf(w1, v1.w, a.w);
        a.x = fmaf(w2, v2.x, a.x); a.y = fmaf(w2, v2.y, a.y);
        a.z = fmaf(w2, v2.z, a.z); a.w = fmaf(w2, v2.w, a.w);
        a.x = fmaf(w3, v3.x, a.x); a.y = fmaf(w3, v3.y, a.y);
        a.z = fmaf(w3, v3.z, a.z); a.w = fmaf(w3, v3.w, a.w);
    }
    for (; j < end; ++j) {
        int s0 = col[j];
        float w0 = wsrc[j];
        float4 v0 = b4f(((const ushort4*)(t + (size_t)s0 * 128))[lane]);
        a.x = fmaf(w0, v0.x, a.x); a.y = fmaf(w0, v0.y, a.y);
        a.z = fmaf(w0, v0.z, a.z); a.w = fmaf(w0, v0.w, a.w);
    }

    float4 bb = ((const float4*)bias)[lane];
    float4 o;
    o.x = fmaf(di, a.x, bb.x); o.y = fmaf(di, a.y, bb.y);
    o.z = fmaf(di, a.z, bb.z); o.w = fmaf(di, a.w, bb.w);
    ((float4*)(out + (size_t)i * 128))[lane] = o;
}

// ---------------- BN stats over node axis ----------------

__global__ __launch_bounds__(256) void k_bnstats(const float* __restrict__ a,
                                                 float* __restrict__ sums, int n) {
    int f = threadIdx.x & 127;
    int g = threadIdx.x >> 7;
    float s = 0.f, q = 0.f;
    for (int i = blockIdx.x * 2 + g; i < n; i += gridDim.x * 2) {
        float v = a[(size_t)i * 128 + f];
        s += v; q = fmaf(v, v, q);
    }
    __shared__ float ls[256], lq[256];
    ls[threadIdx.x] = s; lq[threadIdx.x] = q;
    __syncthreads();
    if (g == 0) {
        atomicAdd(&sums[f], s + ls[128 + f]);
        atomicAdd(&sums[128 + f], q + lq[128 + f]);
    }
}

__global__ void k_bnfinal(const float* __restrict__ sums, const float* __restrict__ gamma,
                          const float* __restrict__ beta, float* __restrict__ scale,
                          float* __restrict__ shift, int n) {
    int f = threadIdx.x;
    float inv_n = 1.f / (float)n;
    float mu = sums[f] * inv_n;
    float var = sums[128 + f] * inv_n - mu * mu;
    float rs = rsqrtf(var + BN_EPS);
    float sc = gamma[f] * rs;
    scale[f] = sc;
    shift[f] = beta[f] - mu * sc;
}

// ---------------- final: 40-wide aggregation (bf16 src) + bias + log_softmax ----------------

__global__ __launch_bounds__(256) void k_agg40(
    const u16* __restrict__ t, const int* __restrict__ roff,
    const int* __restrict__ col, const float* __restrict__ wsrc,
    const float* __restrict__ dinv, const float* __restrict__ bias,
    float* __restrict__ out, int n)
{
    int i = blockIdx.x * 4 + (threadIdx.x >> 6);
    if (i >= n) return;
    int lane = threadIdx.x & 63;
    bool act = lane < NCLS;
    int beg = roff[i], end = roff[i + 1];
    float di = dinv[i];
    float a = act ? di * b2f(t[(size_t)i * NCLS + lane]) : 0.f;
    int j = beg;
    for (; j + 3 < end; j += 4) {
        int s0 = col[j], s1 = col[j + 1], s2 = col[j + 2], s3 = col[j + 3];
        float w0 = wsrc[j], w1 = wsrc[j + 1], w2 = wsrc[j + 2], w3 = wsrc[j + 3];
        float u0 = act ? b2f(t[(size_t)s0 * NCLS + lane]) : 0.f;
        float u1 = act ? b2f(t[(size_t)s1 * NCLS + lane]) : 0.f;
        float u2 = act ? b2f(t[(size_t)s2 * NCLS + lane]) : 0.f;
        float u3 = act ? b2f(t[(size_t)s3 * NCLS + lane]) : 0.f;
        a = fmaf(w0, u0, a); a = fmaf(w1, u1, a);
        a = fmaf(w2, u2, a); a = fmaf(w3, u3, a);
    }
    for (; j < end; ++j) {
        int s0 = col[j];
        float w0 = wsrc[j];
        float u0 = act ? b2f(t[(size_t)s0 * NCLS + lane]) : 0.f;
        a = fmaf(w0, u0, a);
    }
    float v = act ? (fmaf(di, a, bias[lane])) : -INFINITY;
    float m = v;
    for (int d = 32; d > 0; d >>= 1) m = fmaxf(m, __shfl_xor(m, d, 64));
    float e = act ? expf(v - m) : 0.f;
    float ssum = e;
    for (int d = 32; d > 0; d >>= 1) ssum += __shfl_xor(ssum, d, 64);
    if (act) out[(size_t)i * NCLS + lane] = v - m - logf(ssum);
}

// ---------------- launch ----------------

extern "C" void kernel_launch(void* const* d_in, const int* in_sizes, int n_in,
                              void* d_out, int out_size, void* d_ws, size_t ws_size,
                              hipStream_t stream) {
    const float* features = (const float*)d_in[0];
    const int* edge_index = (const int*)d_in[1];
    const float* W1 = (const float*)d_in[2];
    const float* b1 = (const float*)d_in[3];
    const float* gamma1 = (const float*)d_in[4];
    const float* beta1 = (const float*)d_in[5];
    const float* W2 = (const float*)d_in[6];
    const float* b2 = (const float*)d_in[7];
    const float* gamma2 = (const float*)d_in[8];
    const float* beta2 = (const float*)d_in[9];
    const float* W3 = (const float*)d_in[10];
    const float* b3 = (const float*)d_in[11];
    float* out = (float*)d_out;

    int n = in_sizes[0] / FEAT;
    int E = in_sizes[1] / 2;

    char* p = (char*)d_ws;
    auto alloc = [&](size_t bytes) -> void* {
        void* r = (void*)p;
        p += (bytes + 255) & ~(size_t)255;
        return r;
    };
    int* cnt     = (int*)alloc((size_t)n * 4);
    int* row_off = (int*)alloc((size_t)(n + 1) * 4);
    int* cursor  = (int*)alloc((size_t)n * 4);
    int* colb    = (int*)alloc((size_t)E * 4);
    float* wsrc  = (float*)alloc((size_t)E * 4);
    int* bsum    = (int*)alloc(1024);
    int* boff    = (int*)alloc(1024);
    float* dinv  = (float*)alloc((size_t)n * 4);
    float* sums  = (float*)alloc(256 * 4);
    float* scale1 = (float*)alloc(128 * 4);
    float* shift1 = (float*)alloc(128 * 4);
    float* scale2 = (float*)alloc(128 * 4);
    float* shift2 = (float*)alloc(128 * 4);
    u16* hb      = (u16*)alloc((size_t)n * 128 * 2);   // bf16 transform output
    float* ab    = (float*)alloc((size_t)n * 128 * 4); // fp32 aggregated

    const int* e_src = edge_index;
    const int* e_dst = edge_index + E;

    hipMemsetAsync(cnt, 0, (size_t)n * 4, stream);
    k_hist<<<(E + 255) / 256, 256, 0, stream>>>(e_dst, cnt, E);
    int nb = (n + 511) / 512;
    k_scan_a<<<nb, 256, 0, stream>>>(cnt, bsum, n);
    k_scan_b<<<1, 64, 0, stream>>>(bsum, boff, row_off, nb, n);
    k_scan_c<<<nb, 256, 0, stream>>>(cnt, boff, row_off, cursor, dinv, n);
    k_fill<<<(E + 255) / 256, 256, 0, stream>>>(e_src, e_dst, cursor, colb, dinv, wsrc, E);

    int gb64 = (n + 63) / 64;
    int gb8 = (n + 7) / 8;
    int gb4 = (n + 3) / 4;

    // layer 1
    k_gemm128<<<gb64, 256, 0, stream>>>(features, W1, nullptr, nullptr, hb, n);
    k_agg128<<<gb8, 256, 0, stream>>>(hb, row_off, colb, wsrc, dinv, b1, ab, n);
    hipMemsetAsync(sums, 0, 256 * 4, stream);
    k_bnstats<<<128, 256, 0, stream>>>(ab, sums, n);
    k_bnfinal<<<1, 128, 0, stream>>>(sums, gamma1, beta1, scale1, shift1, n);

    // layer 2 (BN1+ReLU fused into GEMM2 input staging)
    k_gemm128<<<gb64, 256, 0, stream>>>(ab, W2, scale1, shift1, hb, n);
    k_agg128<<<gb8, 256, 0, stream>>>(hb, row_off, colb, wsrc, dinv, b2, ab, n);
    hipMemsetAsync(sums, 0, 256 * 4, stream);
    k_bnstats<<<128, 256, 0, stream>>>(ab, sums, n);
    k_bnfinal<<<1, 128, 0, stream>>>(sums, gamma2, beta2, scale2, shift2, n);

    // layer 3: transform first (agg commutes with linear map), then 40-wide agg + log_softmax
    k_gemm40<<<(n + 255) / 256, 256, 0, stream>>>(ab, W3, scale2, shift2, hb, n);
    k_agg40<<<gb4, 256, 0, stream>>>(hb, row_off, colb, wsrc, dinv, b3, out, n);
}

// Round 3
// 471.877 us; speedup vs baseline: 1.2517x; 1.0996x over previous
//
#include <hip/hip_runtime.h>
#include <math.h>

#define FEAT 128
#define NCLS 40
#define BN_EPS 1e-5f

typedef unsigned short u16;
typedef unsigned int u32;

// bf16 helpers (RNE pack, exact unpack)
__device__ inline u32 f2b2(float a, float b) {
    u32 ua = __float_as_uint(a), ub = __float_as_uint(b);
    ua = (ua + 0x7fffu + ((ua >> 16) & 1u)) >> 16;
    ub = (ub + 0x7fffu + ((ub >> 16) & 1u)) >> 16;
    return ua | (ub << 16);
}
__device__ inline float b2f(u16 u) { return __uint_as_float((u32)u << 16); }
__device__ inline float4 b4fv(ushort4 u) {
    return make_float4(b2f(u.x), b2f(u.y), b2f(u.z), b2f(u.w));
}
__device__ inline float blo(u32 u) { return __uint_as_float(u << 16); }
__device__ inline float bhi(u32 u) { return __uint_as_float(u & 0xffff0000u); }

// ---------------- graph prep ----------------

__global__ void k_hist(const int* __restrict__ dst, int* __restrict__ cnt, int E) {
    int e = blockIdx.x * 256 + threadIdx.x;
    if (e < E) atomicAdd(&cnt[dst[e]], 1);
}

__global__ void k_scan_a(const int* __restrict__ cnt, int* __restrict__ bsum, int n) {
    int t = threadIdx.x;
    int idx = blockIdx.x * 512 + t * 2;
    int v = 0;
    if (idx < n) v += cnt[idx];
    if (idx + 1 < n) v += cnt[idx + 1];
    for (int d = 1; d < 64; d <<= 1) v += __shfl_xor(v, d, 64);
    __shared__ int ws[4];
    int lane = t & 63, w = t >> 6;
    if (lane == 0) ws[w] = v;
    __syncthreads();
    if (t == 0) bsum[blockIdx.x] = ws[0] + ws[1] + ws[2] + ws[3];
}

__global__ void k_scan_b(const int* __restrict__ bsum, int* __restrict__ boff,
                         int* __restrict__ row_off, int nb, int n) {
    if (threadIdx.x == 0) {
        int run = 0;
        for (int i = 0; i < nb; ++i) { boff[i] = run; run += bsum[i]; }
        row_off[n] = run;
    }
}

__global__ void k_scan_c(const int* __restrict__ cnt, const int* __restrict__ boff,
                         int* __restrict__ row_off, int* __restrict__ cursor,
                         float* __restrict__ dinv, int n) {
    int t = threadIdx.x;
    int idx = blockIdx.x * 512 + t * 2;
    int v0 = (idx < n) ? cnt[idx] : 0;
    int v1 = (idx + 1 < n) ? cnt[idx + 1] : 0;
    int s = v0 + v1;
    int lane = t & 63, w = t >> 6;
    int incl = s;
    for (int d = 1; d < 64; d <<= 1) {
        int o = __shfl_up(incl, d, 64);
        if (lane >= d) incl += o;
    }
    __shared__ int wsum[4];
    if (lane == 63) wsum[w] = incl;
    __syncthreads();
    int wpre = 0;
    for (int i = 0; i < w; ++i) wpre += wsum[i];
    int base = boff[blockIdx.x] + wpre + incl - s;
    if (idx < n) {
        row_off[idx] = base; cursor[idx] = base;
        dinv[idx] = rsqrtf((float)(v0 + 1));
    }
    if (idx + 1 < n) {
        row_off[idx + 1] = base + v0; cursor[idx + 1] = base + v0;
        dinv[idx + 1] = rsqrtf((float)(v1 + 1));
    }
}

__global__ void k_fill(const int* __restrict__ src, const int* __restrict__ dst,
                       int* __restrict__ cursor, int* __restrict__ col,
                       const float* __restrict__ dinv, float* __restrict__ wsrc, int E) {
    int e = blockIdx.x * 256 + threadIdx.x;
    if (e < E) {
        int s = src[e];
        int p = atomicAdd(&cursor[dst[e]], 1);
        col[p] = s;
        wsrc[p] = dinv[s];
    }
}

// ---------------- GEMM 128x128, fp32 X (layer 1), bf16 out ----------------

__global__ __launch_bounds__(256) void k_gemm128_f32(
    const float* __restrict__ X, const float* __restrict__ W,
    u16* __restrict__ Y, int M)
{
    __shared__ float Wsc[32 * 128];
    __shared__ float Xs[32 * 68];

    int t = threadIdx.x;
    int row0 = blockIdx.x * 64;
    int tx = t & 15, ty = t >> 4;

    float acc[4][8];
#pragma unroll
    for (int r = 0; r < 4; ++r)
#pragma unroll
        for (int c = 0; c < 8; ++c) acc[r][c] = 0.f;

    for (int k0 = 0; k0 < 128; k0 += 32) {
        __syncthreads();
        {
            const float4* W4 = (const float4*)(W + k0 * 128);
            float4* Ws4 = (float4*)Wsc;
#pragma unroll
            for (int i = 0; i < 4; ++i) Ws4[t + i * 256] = W4[t + i * 256];
        }
        {
            int rr = t >> 3;
            int kc = (t & 7) * 4;
#pragma unroll
            for (int p = 0; p < 2; ++p) {
                int r = rr + p * 32;
                int grow = row0 + r;
                float4 v = make_float4(0.f, 0.f, 0.f, 0.f);
                if (grow < M) v = *(const float4*)(X + (size_t)grow * 128 + k0 + kc);
                Xs[(kc + 0) * 68 + r] = v.x;
                Xs[(kc + 1) * 68 + r] = v.y;
                Xs[(kc + 2) * 68 + r] = v.z;
                Xs[(kc + 3) * 68 + r] = v.w;
            }
        }
        __syncthreads();
#pragma unroll 8
        for (int kk = 0; kk < 32; ++kk) {
            const float4 xv = *(const float4*)&Xs[kk * 68 + ty * 4];
            const float4 wa = *(const float4*)&Wsc[kk * 128 + tx * 8];
            const float4 wb = *(const float4*)&Wsc[kk * 128 + tx * 8 + 4];
            const float xr[4] = {xv.x, xv.y, xv.z, xv.w};
            const float wc[8] = {wa.x, wa.y, wa.z, wa.w, wb.x, wb.y, wb.z, wb.w};
#pragma unroll
            for (int r = 0; r < 4; ++r)
#pragma unroll
                for (int c = 0; c < 8; ++c)
                    acc[r][c] = fmaf(xr[r], wc[c], acc[r][c]);
        }
    }

#pragma unroll
    for (int r = 0; r < 4; ++r) {
        int grow = row0 + ty * 4 + r;
        if (grow < M) {
            uint4 o;
            o.x = f2b2(acc[r][0], acc[r][1]);
            o.y = f2b2(acc[r][2], acc[r][3]);
            o.z = f2b2(acc[r][4], acc[r][5]);
            o.w = f2b2(acc[r][6], acc[r][7]);
            *(uint4*)(Y + (size_t)grow * 128 + tx * 8) = o;
        }
    }
}

// ---------------- GEMM 128x128, bf16 X + fused BN+ReLU (layer 2), bf16 out ----------------

__global__ __launch_bounds__(256) void k_gemm128_bf16(
    const u16* __restrict__ X, const float* __restrict__ W,
    const float* __restrict__ scale, const float* __restrict__ shift,
    u16* __restrict__ Y, int M)
{
    __shared__ float Wsc[32 * 128];
    __shared__ float Xs[32 * 68];

    int t = threadIdx.x;
    int row0 = blockIdx.x * 64;
    int tx = t & 15, ty = t >> 4;

    float acc[4][8];
#pragma unroll
    for (int r = 0; r < 4; ++r)
#pragma unroll
        for (int c = 0; c < 8; ++c) acc[r][c] = 0.f;

    for (int k0 = 0; k0 < 128; k0 += 32) {
        __syncthreads();
        {
            const float4* W4 = (const float4*)(W + k0 * 128);
            float4* Ws4 = (float4*)Wsc;
#pragma unroll
            for (int i = 0; i < 4; ++i) Ws4[t + i * 256] = W4[t + i * 256];
        }
        {
            int rr = t >> 3;
            int kc = (t & 7) * 4;
            float4 sc = *(const float4*)(scale + k0 + kc);
            float4 sh = *(const float4*)(shift + k0 + kc);
#pragma unroll
            for (int p = 0; p < 2; ++p) {
                int r = rr + p * 32;
                int grow = row0 + r;
                float4 v = make_float4(0.f, 0.f, 0.f, 0.f);
                if (grow < M) v = b4fv(*(const ushort4*)(X + (size_t)grow * 128 + k0 + kc));
                v.x = fmaxf(fmaf(v.x, sc.x, sh.x), 0.f);
                v.y = fmaxf(fmaf(v.y, sc.y, sh.y), 0.f);
                v.z = fmaxf(fmaf(v.z, sc.z, sh.z), 0.f);
                v.w = fmaxf(fmaf(v.w, sc.w, sh.w), 0.f);
                Xs[(kc + 0) * 68 + r] = v.x;
                Xs[(kc + 1) * 68 + r] = v.y;
                Xs[(kc + 2) * 68 + r] = v.z;
                Xs[(kc + 3) * 68 + r] = v.w;
            }
        }
        __syncthreads();
#pragma unroll 8
        for (int kk = 0; kk < 32; ++kk) {
            const float4 xv = *(const float4*)&Xs[kk * 68 + ty * 4];
            const float4 wa = *(const float4*)&Wsc[kk * 128 + tx * 8];
            const float4 wb = *(const float4*)&Wsc[kk * 128 + tx * 8 + 4];
            const float xr[4] = {xv.x, xv.y, xv.z, xv.w};
            const float wc[8] = {wa.x, wa.y, wa.z, wa.w, wb.x, wb.y, wb.z, wb.w};
#pragma unroll
            for (int r = 0; r < 4; ++r)
#pragma unroll
                for (int c = 0; c < 8; ++c)
                    acc[r][c] = fmaf(xr[r], wc[c], acc[r][c]);
        }
    }

#pragma unroll
    for (int r = 0; r < 4; ++r) {
        int grow = row0 + ty * 4 + r;
        if (grow < M) {
            uint4 o;
            o.x = f2b2(acc[r][0], acc[r][1]);
            o.y = f2b2(acc[r][2], acc[r][3]);
            o.z = f2b2(acc[r][4], acc[r][5]);
            o.w = f2b2(acc[r][6], acc[r][7]);
            *(uint4*)(Y + (size_t)grow * 128 + tx * 8) = o;
        }
    }
}

// ---------------- GEMM 128->40, bf16 X + fused BN+ReLU, bf16 out ----------------

__global__ __launch_bounds__(256) void k_gemm40(
    const u16* __restrict__ X, const float* __restrict__ W,
    const float* __restrict__ scale, const float* __restrict__ shift,
    u16* __restrict__ Y, int M)
{
    __shared__ float Ws[128 * 40];
    __shared__ float Xs[32 * 260];

    int t = threadIdx.x;
    int row0 = blockIdx.x * 256;
    int tx = t & 3, ty = t >> 2;

    {
        const float4* W4 = (const float4*)W;
        float4* Ws4 = (float4*)Ws;
#pragma unroll
        for (int i = 0; i < 5; ++i) Ws4[t + i * 256] = W4[t + i * 256];
    }

    float acc[4][10];
#pragma unroll
    for (int r = 0; r < 4; ++r)
#pragma unroll
        for (int c = 0; c < 10; ++c) acc[r][c] = 0.f;

    for (int k0 = 0; k0 < 128; k0 += 32) {
        __syncthreads();
        {
            int rr = t >> 3;
            int kc = (t & 7) * 4;
            float4 sc = *(const float4*)(scale + k0 + kc);
            float4 sh = *(const float4*)(shift + k0 + kc);
#pragma unroll
            for (int p = 0; p < 8; ++p) {
                int r = rr + p * 32;
                int grow = row0 + r;
                float4 v = make_float4(0.f, 0.f, 0.f, 0.f);
                if (grow < M) v = b4fv(*(const ushort4*)(X + (size_t)grow * 128 + k0 + kc));
                v.x = fmaxf(fmaf(v.x, sc.x, sh.x), 0.f);
                v.y = fmaxf(fmaf(v.y, sc.y, sh.y), 0.f);
                v.z = fmaxf(fmaf(v.z, sc.z, sh.z), 0.f);
                v.w = fmaxf(fmaf(v.w, sc.w, sh.w), 0.f);
                Xs[(kc + 0) * 260 + r] = v.x;
                Xs[(kc + 1) * 260 + r] = v.y;
                Xs[(kc + 2) * 260 + r] = v.z;
                Xs[(kc + 3) * 260 + r] = v.w;
            }
        }
        __syncthreads();
#pragma unroll 8
        for (int kk = 0; kk < 32; ++kk) {
            const float4 xv = *(const float4*)&Xs[kk * 260 + ty * 4];
            const float xr[4] = {xv.x, xv.y, xv.z, xv.w};
            float wc[10];
#pragma unroll
            for (int c = 0; c < 5; ++c) {
                float2 w2 = *(const float2*)&Ws[(k0 + kk) * 40 + tx * 10 + c * 2];
                wc[c * 2] = w2.x; wc[c * 2 + 1] = w2.y;
            }
#pragma unroll
            for (int r = 0; r < 4; ++r)
#pragma unroll
                for (int c = 0; c < 10; ++c)
                    acc[r][c] = fmaf(xr[r], wc[c], acc[r][c]);
        }
    }

#pragma unroll
    for (int r = 0; r < 4; ++r) {
        int grow = row0 + ty * 4 + r;
        if (grow < M) {
            u32* yp = (u32*)(Y + (size_t)grow * 40 + tx * 10);
#pragma unroll
            for (int c = 0; c < 5; ++c)
                yp[c] = f2b2(acc[r][c * 2], acc[r][c * 2 + 1]);
        }
    }
}

// ---------------- aggregation 128-wide (bf16 src, fp32 accum, bf16 out) ----------------
// out[i] = dinv[i]*(sum_e w_e*t[s_e] + dinv[i]*t[i]) + b; 32 lanes/node, 2 nodes/wave.

__global__ __launch_bounds__(256) void k_agg128(
    const u16* __restrict__ t, const int* __restrict__ roff,
    const int* __restrict__ col, const float* __restrict__ wsrc,
    const float* __restrict__ dinv, const float* __restrict__ bias,
    u16* __restrict__ out, int n)
{
    int i = blockIdx.x * 8 + (threadIdx.x >> 5);
    if (i >= n) return;
    int lane = threadIdx.x & 31;
    int beg = roff[i], end = roff[i + 1];
    float di = dinv[i];

    float4 s4 = b4fv(((const ushort4*)(t + (size_t)i * 128))[lane]);
    float4 a = make_float4(di * s4.x, di * s4.y, di * s4.z, di * s4.w);

    int j = beg;
    for (; j + 7 < end; j += 8) {
        int s[8]; float w[8]; ushort4 v[8];
#pragma unroll
        for (int k = 0; k < 8; ++k) { s[k] = col[j + k]; w[k] = wsrc[j + k]; }
#pragma unroll
        for (int k = 0; k < 8; ++k) v[k] = ((const ushort4*)(t + (size_t)s[k] * 128))[lane];
#pragma unroll
        for (int k = 0; k < 8; ++k) {
            float4 f = b4fv(v[k]);
            a.x = fmaf(w[k], f.x, a.x); a.y = fmaf(w[k], f.y, a.y);
            a.z = fmaf(w[k], f.z, a.z); a.w = fmaf(w[k], f.w, a.w);
        }
    }
    for (; j < end; ++j) {
        float w0 = wsrc[j];
        float4 f = b4fv(((const ushort4*)(t + (size_t)col[j] * 128))[lane]);
        a.x = fmaf(w0, f.x, a.x); a.y = fmaf(w0, f.y, a.y);
        a.z = fmaf(w0, f.z, a.z); a.w = fmaf(w0, f.w, a.w);
    }

    float4 bb = ((const float4*)bias)[lane];
    uint2 o;
    o.x = f2b2(fmaf(di, a.x, bb.x), fmaf(di, a.y, bb.y));
    o.y = f2b2(fmaf(di, a.z, bb.z), fmaf(di, a.w, bb.w));
    ((uint2*)(out + (size_t)i * 128))[lane] = o;
}

// ---------------- BN stats over node axis (bf16 input) ----------------

__global__ __launch_bounds__(256) void k_bnstats(const u16* __restrict__ a,
                                                 float* __restrict__ sums, int n) {
    int f = threadIdx.x & 127;
    int g = threadIdx.x >> 7;
    float s = 0.f, q = 0.f;
    for (int i = blockIdx.x * 2 + g; i < n; i += gridDim.x * 2) {
        float v = b2f(a[(size_t)i * 128 + f]);
        s += v; q = fmaf(v, v, q);
    }
    __shared__ float ls[256], lq[256];
    ls[threadIdx.x] = s; lq[threadIdx.x] = q;
    __syncthreads();
    if (g == 0) {
        atomicAdd(&sums[f], s + ls[128 + f]);
        atomicAdd(&sums[128 + f], q + lq[128 + f]);
    }
}

__global__ void k_bnfinal(const float* __restrict__ sums, const float* __restrict__ gamma,
                          const float* __restrict__ beta, float* __restrict__ scale,
                          float* __restrict__ shift, int n) {
    int f = threadIdx.x;
    float inv_n = 1.f / (float)n;
    float mu = sums[f] * inv_n;
    float var = sums[128 + f] * inv_n - mu * mu;
    float rs = rsqrtf(var + BN_EPS);
    float sc = gamma[f] * rs;
    scale[f] = sc;
    shift[f] = beta[f] - mu * sc;
}

// ---------------- final: 40-wide agg (bf16 src) + bias + log_softmax ----------------
// 2 nodes per wave: 32-lane groups, lanes 0..19 hold classes {2l, 2l+1} as one u32.

__global__ __launch_bounds__(256) void k_agg40(
    const u16* __restrict__ t, const int* __restrict__ roff,
    const int* __restrict__ col, const float* __restrict__ wsrc,
    const float* __restrict__ dinv, const float* __restrict__ bias,
    float* __restrict__ out, int n)
{
    int i = blockIdx.x * 8 + (threadIdx.x >> 5);
    if (i >= n) return;
    int l = threadIdx.x & 31;
    bool act = l < 20;
    int beg = roff[i], end = roff[i + 1];
    float di = dinv[i];

    float ax = 0.f, ay = 0.f;
    if (act) {
        u32 u = ((const u32*)(t + (size_t)i * NCLS))[l];
        ax = di * blo(u); ay = di * bhi(u);
    }
    int j = beg;
    for (; j + 7 < end; j += 8) {
        int s[8]; float w[8]; u32 u[8];
#pragma unroll
        for (int k = 0; k < 8; ++k) { s[k] = col[j + k]; w[k] = wsrc[j + k]; }
#pragma unroll
        for (int k = 0; k < 8; ++k)
            u[k] = act ? ((const u32*)(t + (size_t)s[k] * NCLS))[l] : 0u;
#pragma unroll
        for (int k = 0; k < 8; ++k) {
            ax = fmaf(w[k], blo(u[k]), ax);
            ay = fmaf(w[k], bhi(u[k]), ay);
        }
    }
    for (; j < end; ++j) {
        float w0 = wsrc[j];
        u32 u = act ? ((const u32*)(t + (size_t)col[j] * NCLS))[l] : 0u;
        ax = fmaf(w0, blo(u), ax);
        ay = fmaf(w0, bhi(u), ay);
    }

    float v0 = -INFINITY, v1 = -INFINITY;
    if (act) {
        float2 bb = ((const float2*)bias)[l];
        v0 = fmaf(di, ax, bb.x);
        v1 = fmaf(di, ay, bb.y);
    }
    float m = fmaxf(v0, v1);
#pragma unroll
    for (int d = 16; d > 0; d >>= 1) m = fmaxf(m, __shfl_xor(m, d, 32));
    float e = act ? (expf(v0 - m) + expf(v1 - m)) : 0.f;
    float ssum = e;
#pragma unroll
    for (int d = 16; d > 0; d >>= 1) ssum += __shfl_xor(ssum, d, 32);
    float ls = logf(ssum);
    if (act) {
        float2 o; o.x = v0 - m - ls; o.y = v1 - m - ls;
        ((float2*)(out + (size_t)i * NCLS))[l] = o;
    }
}

// ---------------- launch ----------------

extern "C" void kernel_launch(void* const* d_in, const int* in_sizes, int n_in,
                              void* d_out, int out_size, void* d_ws, size_t ws_size,
                              hipStream_t stream) {
    const float* features = (const float*)d_in[0];
    const int* edge_index = (const int*)d_in[1];
    const float* W1 = (const float*)d_in[2];
    const float* b1 = (const float*)d_in[3];
    const float* gamma1 = (const float*)d_in[4];
    const float* beta1 = (const float*)d_in[5];
    const float* W2 = (const float*)d_in[6];
    const float* b2 = (const float*)d_in[7];
    const float* gamma2 = (const float*)d_in[8];
    const float* beta2 = (const float*)d_in[9];
    const float* W3 = (const float*)d_in[10];
    const float* b3 = (const float*)d_in[11];
    float* out = (float*)d_out;

    int n = in_sizes[0] / FEAT;
    int E = in_sizes[1] / 2;

    char* p = (char*)d_ws;
    auto alloc = [&](size_t bytes) -> void* {
        void* r = (void*)p;
        p += (bytes + 255) & ~(size_t)255;
        return r;
    };
    int* cnt     = (int*)alloc((size_t)n * 4);
    int* row_off = (int*)alloc((size_t)(n + 1) * 4);
    int* cursor  = (int*)alloc((size_t)n * 4);
    int* colb    = (int*)alloc((size_t)E * 4);
    float* wsrc  = (float*)alloc((size_t)E * 4);
    int* bsum    = (int*)alloc(1024);
    int* boff    = (int*)alloc(1024);
    float* dinv  = (float*)alloc((size_t)n * 4);
    float* sums  = (float*)alloc(256 * 4);
    float* scale1 = (float*)alloc(128 * 4);
    float* shift1 = (float*)alloc(128 * 4);
    float* scale2 = (float*)alloc(128 * 4);
    float* shift2 = (float*)alloc(128 * 4);
    u16* hb      = (u16*)alloc((size_t)n * 128 * 2);   // transform output (bf16)
    u16* ab      = (u16*)alloc((size_t)n * 128 * 2);   // aggregated (bf16)

    const int* e_src = edge_index;
    const int* e_dst = edge_index + E;

    hipMemsetAsync(cnt, 0, (size_t)n * 4, stream);
    k_hist<<<(E + 255) / 256, 256, 0, stream>>>(e_dst, cnt, E);
    int nb = (n + 511) / 512;
    k_scan_a<<<nb, 256, 0, stream>>>(cnt, bsum, n);
    k_scan_b<<<1, 64, 0, stream>>>(bsum, boff, row_off, nb, n);
    k_scan_c<<<nb, 256, 0, stream>>>(cnt, boff, row_off, cursor, dinv, n);
    k_fill<<<(E + 255) / 256, 256, 0, stream>>>(e_src, e_dst, cursor, colb, dinv, wsrc, E);

    int gb64 = (n + 63) / 64;
    int gb8 = (n + 7) / 8;

    // layer 1
    k_gemm128_f32<<<gb64, 256, 0, stream>>>(features, W1, hb, n);
    k_agg128<<<gb8, 256, 0, stream>>>(hb, row_off, colb, wsrc, dinv, b1, ab, n);
    hipMemsetAsync(sums, 0, 256 * 4, stream);
    k_bnstats<<<128, 256, 0, stream>>>(ab, sums, n);
    k_bnfinal<<<1, 128, 0, stream>>>(sums, gamma1, beta1, scale1, shift1, n);

    // layer 2 (BN1+ReLU fused into GEMM2 input staging)
    k_gemm128_bf16<<<gb64, 256, 0, stream>>>(ab, W2, scale1, shift1, hb, n);
    k_agg128<<<gb8, 256, 0, stream>>>(hb, row_off, colb, wsrc, dinv, b2, ab, n);
    hipMemsetAsync(sums, 0, 256 * 4, stream);
    k_bnstats<<<128, 256, 0, stream>>>(ab, sums, n);
    k_bnfinal<<<1, 128, 0, stream>>>(sums, gamma2, beta2, scale2, shift2, n);

    // layer 3: transform first, then 40-wide agg + log_softmax
    k_gemm40<<<(n + 255) / 256, 256, 0, stream>>>(ab, W3, scale2, shift2, hb, n);
    k_agg40<<<gb8, 256, 0, stream>>>(hb, row_off, colb, wsrc, dinv, b3, out, n);
}

// Round 4
// 436.623 us; speedup vs baseline: 1.3528x; 1.0807x over previous
//
#include <hip/hip_runtime.h>
#include <math.h>

#define FEAT 128
#define NCLS 40
#define BN_EPS 1e-5f

typedef unsigned short u16;
typedef unsigned int u32;

// bf16 helpers (RNE pack, exact unpack)
__device__ inline u32 f2b2(float a, float b) {
    u32 ua = __float_as_uint(a), ub = __float_as_uint(b);
    ua = (ua + 0x7fffu + ((ua >> 16) & 1u)) >> 16;
    ub = (ub + 0x7fffu + ((ub >> 16) & 1u)) >> 16;
    return ua | (ub << 16);
}
__device__ inline float b2f(u16 u) { return __uint_as_float((u32)u << 16); }
__device__ inline float4 b4fv(ushort4 u) {
    return make_float4(b2f(u.x), b2f(u.y), b2f(u.z), b2f(u.w));
}
__device__ inline float blo(u32 u) { return __uint_as_float(u << 16); }
__device__ inline float bhi(u32 u) { return __uint_as_float(u & 0xffff0000u); }

// ---------------- graph prep ----------------

__global__ void k_hist(const int* __restrict__ dst, int* __restrict__ cnt, int E) {
    int e = blockIdx.x * 256 + threadIdx.x;
    if (e < E) atomicAdd(&cnt[dst[e]], 1);
}

__global__ void k_scan_a(const int* __restrict__ cnt, int* __restrict__ bsum, int n) {
    int t = threadIdx.x;
    int idx = blockIdx.x * 512 + t * 2;
    int v = 0;
    if (idx < n) v += cnt[idx];
    if (idx + 1 < n) v += cnt[idx + 1];
    for (int d = 1; d < 64; d <<= 1) v += __shfl_xor(v, d, 64);
    __shared__ int ws[4];
    int lane = t & 63, w = t >> 6;
    if (lane == 0) ws[w] = v;
    __syncthreads();
    if (t == 0) bsum[blockIdx.x] = ws[0] + ws[1] + ws[2] + ws[3];
}

__global__ void k_scan_b(const int* __restrict__ bsum, int* __restrict__ boff,
                         int* __restrict__ row_off, int nb, int n) {
    if (threadIdx.x == 0) {
        int run = 0;
        for (int i = 0; i < nb; ++i) { boff[i] = run; run += bsum[i]; }
        row_off[n] = run;
    }
}

__global__ void k_scan_c(const int* __restrict__ cnt, const int* __restrict__ boff,
                         int* __restrict__ row_off, int* __restrict__ cursor,
                         float* __restrict__ dinv, int n) {
    int t = threadIdx.x;
    int idx = blockIdx.x * 512 + t * 2;
    int v0 = (idx < n) ? cnt[idx] : 0;
    int v1 = (idx + 1 < n) ? cnt[idx + 1] : 0;
    int s = v0 + v1;
    int lane = t & 63, w = t >> 6;
    int incl = s;
    for (int d = 1; d < 64; d <<= 1) {
        int o = __shfl_up(incl, d, 64);
        if (lane >= d) incl += o;
    }
    __shared__ int wsum[4];
    if (lane == 63) wsum[w] = incl;
    __syncthreads();
    int wpre = 0;
    for (int i = 0; i < w; ++i) wpre += wsum[i];
    int base = boff[blockIdx.x] + wpre + incl - s;
    if (idx < n) {
        row_off[idx] = base; cursor[idx] = base;
        dinv[idx] = rsqrtf((float)(v0 + 1));
    }
    if (idx + 1 < n) {
        row_off[idx + 1] = base + v0; cursor[idx + 1] = base + v0;
        dinv[idx + 1] = rsqrtf((float)(v1 + 1));
    }
}

// CSR fill: col only (dinv[src] is re-gathered from the L2-resident table in agg;
// storing a per-edge weight doubled the random-scatter writeback lines: 82 MB -> WRITE bound)
__global__ void k_fill(const int* __restrict__ src, const int* __restrict__ dst,
                       int* __restrict__ cursor, int* __restrict__ col, int E) {
    int e = blockIdx.x * 256 + threadIdx.x;
    if (e < E) {
        int p = atomicAdd(&cursor[dst[e]], 1);
        col[p] = src[e];
    }
}

// ---------------- GEMM 128x128, fp32 X (layer 1), bf16 out ----------------

__global__ __launch_bounds__(256) void k_gemm128_f32(
    const float* __restrict__ X, const float* __restrict__ W,
    u16* __restrict__ Y, int M)
{
    __shared__ float Wsc[32 * 128];
    __shared__ float Xs[32 * 68];

    int t = threadIdx.x;
    int row0 = blockIdx.x * 64;
    int tx = t & 15, ty = t >> 4;

    float acc[4][8];
#pragma unroll
    for (int r = 0; r < 4; ++r)
#pragma unroll
        for (int c = 0; c < 8; ++c) acc[r][c] = 0.f;

    for (int k0 = 0; k0 < 128; k0 += 32) {
        __syncthreads();
        {
            const float4* W4 = (const float4*)(W + k0 * 128);
            float4* Ws4 = (float4*)Wsc;
#pragma unroll
            for (int i = 0; i < 4; ++i) Ws4[t + i * 256] = W4[t + i * 256];
        }
        {
            int rr = t >> 3;
            int kc = (t & 7) * 4;
#pragma unroll
            for (int p = 0; p < 2; ++p) {
                int r = rr + p * 32;
                int grow = row0 + r;
                float4 v = make_float4(0.f, 0.f, 0.f, 0.f);
                if (grow < M) v = *(const float4*)(X + (size_t)grow * 128 + k0 + kc);
                Xs[(kc + 0) * 68 + r] = v.x;
                Xs[(kc + 1) * 68 + r] = v.y;
                Xs[(kc + 2) * 68 + r] = v.z;
                Xs[(kc + 3) * 68 + r] = v.w;
            }
        }
        __syncthreads();
#pragma unroll 8
        for (int kk = 0; kk < 32; ++kk) {
            const float4 xv = *(const float4*)&Xs[kk * 68 + ty * 4];
            const float4 wa = *(const float4*)&Wsc[kk * 128 + tx * 8];
            const float4 wb = *(const float4*)&Wsc[kk * 128 + tx * 8 + 4];
            const float xr[4] = {xv.x, xv.y, xv.z, xv.w};
            const float wc[8] = {wa.x, wa.y, wa.z, wa.w, wb.x, wb.y, wb.z, wb.w};
#pragma unroll
            for (int r = 0; r < 4; ++r)
#pragma unroll
                for (int c = 0; c < 8; ++c)
                    acc[r][c] = fmaf(xr[r], wc[c], acc[r][c]);
        }
    }

#pragma unroll
    for (int r = 0; r < 4; ++r) {
        int grow = row0 + ty * 4 + r;
        if (grow < M) {
            uint4 o;
            o.x = f2b2(acc[r][0], acc[r][1]);
            o.y = f2b2(acc[r][2], acc[r][3]);
            o.z = f2b2(acc[r][4], acc[r][5]);
            o.w = f2b2(acc[r][6], acc[r][7]);
            *(uint4*)(Y + (size_t)grow * 128 + tx * 8) = o;
        }
    }
}

// ---------------- GEMM 128x128, bf16 X + fused BN+ReLU (layer 2), bf16 out ----------------

__global__ __launch_bounds__(256) void k_gemm128_bf16(
    const u16* __restrict__ X, const float* __restrict__ W,
    const float* __restrict__ scale, const float* __restrict__ shift,
    u16* __restrict__ Y, int M)
{
    __shared__ float Wsc[32 * 128];
    __shared__ float Xs[32 * 68];

    int t = threadIdx.x;
    int row0 = blockIdx.x * 64;
    int tx = t & 15, ty = t >> 4;

    float acc[4][8];
#pragma unroll
    for (int r = 0; r < 4; ++r)
#pragma unroll
        for (int c = 0; c < 8; ++c) acc[r][c] = 0.f;

    for (int k0 = 0; k0 < 128; k0 += 32) {
        __syncthreads();
        {
            const float4* W4 = (const float4*)(W + k0 * 128);
            float4* Ws4 = (float4*)Wsc;
#pragma unroll
            for (int i = 0; i < 4; ++i) Ws4[t + i * 256] = W4[t + i * 256];
        }
        {
            int rr = t >> 3;
            int kc = (t & 7) * 4;
            float4 sc = *(const float4*)(scale + k0 + kc);
            float4 sh = *(const float4*)(shift + k0 + kc);
#pragma unroll
            for (int p = 0; p < 2; ++p) {
                int r = rr + p * 32;
                int grow = row0 + r;
                float4 v = make_float4(0.f, 0.f, 0.f, 0.f);
                if (grow < M) v = b4fv(*(const ushort4*)(X + (size_t)grow * 128 + k0 + kc));
                v.x = fmaxf(fmaf(v.x, sc.x, sh.x), 0.f);
                v.y = fmaxf(fmaf(v.y, sc.y, sh.y), 0.f);
                v.z = fmaxf(fmaf(v.z, sc.z, sh.z), 0.f);
                v.w = fmaxf(fmaf(v.w, sc.w, sh.w), 0.f);
                Xs[(kc + 0) * 68 + r] = v.x;
                Xs[(kc + 1) * 68 + r] = v.y;
                Xs[(kc + 2) * 68 + r] = v.z;
                Xs[(kc + 3) * 68 + r] = v.w;
            }
        }
        __syncthreads();
#pragma unroll 8
        for (int kk = 0; kk < 32; ++kk) {
            const float4 xv = *(const float4*)&Xs[kk * 68 + ty * 4];
            const float4 wa = *(const float4*)&Wsc[kk * 128 + tx * 8];
            const float4 wb = *(const float4*)&Wsc[kk * 128 + tx * 8 + 4];
            const float xr[4] = {xv.x, xv.y, xv.z, xv.w};
            const float wc[8] = {wa.x, wa.y, wa.z, wa.w, wb.x, wb.y, wb.z, wb.w};
#pragma unroll
            for (int r = 0; r < 4; ++r)
#pragma unroll
                for (int c = 0; c < 8; ++c)
                    acc[r][c] = fmaf(xr[r], wc[c], acc[r][c]);
        }
    }

#pragma unroll
    for (int r = 0; r < 4; ++r) {
        int grow = row0 + ty * 4 + r;
        if (grow < M) {
            uint4 o;
            o.x = f2b2(acc[r][0], acc[r][1]);
            o.y = f2b2(acc[r][2], acc[r][3]);
            o.z = f2b2(acc[r][4], acc[r][5]);
            o.w = f2b2(acc[r][6], acc[r][7]);
            *(uint4*)(Y + (size_t)grow * 128 + tx * 8) = o;
        }
    }
}

// ---------------- GEMM 128->40, bf16 X + fused BN+ReLU, bf16 out ----------------

__global__ __launch_bounds__(256) void k_gemm40(
    const u16* __restrict__ X, const float* __restrict__ W,
    const float* __restrict__ scale, const float* __restrict__ shift,
    u16* __restrict__ Y, int M)
{
    __shared__ float Ws[128 * 40];
    __shared__ float Xs[32 * 260];

    int t = threadIdx.x;
    int row0 = blockIdx.x * 256;
    int tx = t & 3, ty = t >> 2;

    {
        const float4* W4 = (const float4*)W;
        float4* Ws4 = (float4*)Ws;
#pragma unroll
        for (int i = 0; i < 5; ++i) Ws4[t + i * 256] = W4[t + i * 256];
    }

    float acc[4][10];
#pragma unroll
    for (int r = 0; r < 4; ++r)
#pragma unroll
        for (int c = 0; c < 10; ++c) acc[r][c] = 0.f;

    for (int k0 = 0; k0 < 128; k0 += 32) {
        __syncthreads();
        {
            int rr = t >> 3;
            int kc = (t & 7) * 4;
            float4 sc = *(const float4*)(scale + k0 + kc);
            float4 sh = *(const float4*)(shift + k0 + kc);
#pragma unroll
            for (int p = 0; p < 8; ++p) {
                int r = rr + p * 32;
                int grow = row0 + r;
                float4 v = make_float4(0.f, 0.f, 0.f, 0.f);
                if (grow < M) v = b4fv(*(const ushort4*)(X + (size_t)grow * 128 + k0 + kc));
                v.x = fmaxf(fmaf(v.x, sc.x, sh.x), 0.f);
                v.y = fmaxf(fmaf(v.y, sc.y, sh.y), 0.f);
                v.z = fmaxf(fmaf(v.z, sc.z, sh.z), 0.f);
                v.w = fmaxf(fmaf(v.w, sc.w, sh.w), 0.f);
                Xs[(kc + 0) * 260 + r] = v.x;
                Xs[(kc + 1) * 260 + r] = v.y;
                Xs[(kc + 2) * 260 + r] = v.z;
                Xs[(kc + 3) * 260 + r] = v.w;
            }
        }
        __syncthreads();
#pragma unroll 8
        for (int kk = 0; kk < 32; ++kk) {
            const float4 xv = *(const float4*)&Xs[kk * 260 + ty * 4];
            const float xr[4] = {xv.x, xv.y, xv.z, xv.w};
            float wc[10];
#pragma unroll
            for (int c = 0; c < 5; ++c) {
                float2 w2 = *(const float2*)&Ws[(k0 + kk) * 40 + tx * 10 + c * 2];
                wc[c * 2] = w2.x; wc[c * 2 + 1] = w2.y;
            }
#pragma unroll
            for (int r = 0; r < 4; ++r)
#pragma unroll
                for (int c = 0; c < 10; ++c)
                    acc[r][c] = fmaf(xr[r], wc[c], acc[r][c]);
        }
    }

#pragma unroll
    for (int r = 0; r < 4; ++r) {
        int grow = row0 + ty * 4 + r;
        if (grow < M) {
            u32* yp = (u32*)(Y + (size_t)grow * 40 + tx * 10);
#pragma unroll
            for (int c = 0; c < 5; ++c)
                yp[c] = f2b2(acc[r][c * 2], acc[r][c * 2 + 1]);
        }
    }
}

// ---------------- aggregation 128-wide + fused BN stats ----------------
// out[i] = dinv[i]*(sum_e dinv[s_e]*t[s_e] + dinv[i]*t[i]) + b
// 32 lanes/node, 8 nodes per block, grid-stride; per-thread sum/sumsq
// accumulators reduced via LDS, one atomicAdd per feature per block.

__global__ __launch_bounds__(256) void k_agg128(
    const u16* __restrict__ t, const int* __restrict__ roff,
    const int* __restrict__ col, const float* __restrict__ dinv,
    const float* __restrict__ bias, u16* __restrict__ out,
    float* __restrict__ sums, int n, int ngroups)
{
    int wid = threadIdx.x >> 5;
    int lane = threadIdx.x & 31;
    float4 bb = ((const float4*)bias)[lane];

    float st_s[4] = {0.f, 0.f, 0.f, 0.f};
    float st_q[4] = {0.f, 0.f, 0.f, 0.f};

    for (int g = blockIdx.x; g < ngroups; g += gridDim.x) {
        int i = g * 8 + wid;
        if (i >= n) continue;
        int beg = roff[i], end = roff[i + 1];
        float di = dinv[i];

        float4 s4 = b4fv(((const ushort4*)(t + (size_t)i * 128))[lane]);
        float4 a = make_float4(di * s4.x, di * s4.y, di * s4.z, di * s4.w);

        int j = beg;
        for (; j + 7 < end; j += 8) {
            int s[8]; float w[8]; ushort4 v[8];
#pragma unroll
            for (int k = 0; k < 8; ++k) s[k] = col[j + k];
#pragma unroll
            for (int k = 0; k < 8; ++k) {
                w[k] = dinv[s[k]];
                v[k] = ((const ushort4*)(t + (size_t)s[k] * 128))[lane];
            }
#pragma unroll
            for (int k = 0; k < 8; ++k) {
                float4 f = b4fv(v[k]);
                a.x = fmaf(w[k], f.x, a.x); a.y = fmaf(w[k], f.y, a.y);
                a.z = fmaf(w[k], f.z, a.z); a.w = fmaf(w[k], f.w, a.w);
            }
        }
        for (; j < end; ++j) {
            int s0 = col[j];
            float w0 = dinv[s0];
            float4 f = b4fv(((const ushort4*)(t + (size_t)s0 * 128))[lane]);
            a.x = fmaf(w0, f.x, a.x); a.y = fmaf(w0, f.y, a.y);
            a.z = fmaf(w0, f.z, a.z); a.w = fmaf(w0, f.w, a.w);
        }

        float ox = fmaf(di, a.x, bb.x), oy = fmaf(di, a.y, bb.y);
        float oz = fmaf(di, a.z, bb.z), ow = fmaf(di, a.w, bb.w);

        st_s[0] += ox; st_s[1] += oy; st_s[2] += oz; st_s[3] += ow;
        st_q[0] = fmaf(ox, ox, st_q[0]); st_q[1] = fmaf(oy, oy, st_q[1]);
        st_q[2] = fmaf(oz, oz, st_q[2]); st_q[3] = fmaf(ow, ow, st_q[3]);

        uint2 o;
        o.x = f2b2(ox, oy);
        o.y = f2b2(oz, ow);
        ((uint2*)(out + (size_t)i * 128))[lane] = o;
    }

    // block reduction of stats: feature f = lane*4 + k, over the 8 waves
    __shared__ float red[8][128];
#pragma unroll
    for (int k = 0; k < 4; ++k) red[wid][lane * 4 + k] = st_s[k];
    __syncthreads();
    if (threadIdx.x < 128) {
        float v = 0.f;
#pragma unroll
        for (int w = 0; w < 8; ++w) v += red[w][threadIdx.x];
        atomicAdd(&sums[threadIdx.x], v);
    }
    __syncthreads();
#pragma unroll
    for (int k = 0; k < 4; ++k) red[wid][lane * 4 + k] = st_q[k];
    __syncthreads();
    if (threadIdx.x < 128) {
        float v = 0.f;
#pragma unroll
        for (int w = 0; w < 8; ++w) v += red[w][threadIdx.x];
        atomicAdd(&sums[128 + threadIdx.x], v);
    }
}

__global__ void k_bnfinal(const float* __restrict__ sums, const float* __restrict__ gamma,
                          const float* __restrict__ beta, float* __restrict__ scale,
                          float* __restrict__ shift, int n) {
    int f = threadIdx.x;
    float inv_n = 1.f / (float)n;
    float mu = sums[f] * inv_n;
    float var = sums[128 + f] * inv_n - mu * mu;
    float rs = rsqrtf(var + BN_EPS);
    float sc = gamma[f] * rs;
    scale[f] = sc;
    shift[f] = beta[f] - mu * sc;
}

// ---------------- final: 40-wide agg (bf16 src) + bias + log_softmax ----------------
// 2 nodes per wave: 32-lane groups, lanes 0..19 hold classes {2l, 2l+1} as one u32.

__global__ __launch_bounds__(256) void k_agg40(
    const u16* __restrict__ t, const int* __restrict__ roff,
    const int* __restrict__ col, const float* __restrict__ dinv,
    const float* __restrict__ bias, float* __restrict__ out, int n)
{
    int i = blockIdx.x * 8 + (threadIdx.x >> 5);
    if (i >= n) return;
    int l = threadIdx.x & 31;
    bool act = l < 20;
    int beg = roff[i], end = roff[i + 1];
    float di = dinv[i];

    float ax = 0.f, ay = 0.f;
    if (act) {
        u32 u = ((const u32*)(t + (size_t)i * NCLS))[l];
        ax = di * blo(u); ay = di * bhi(u);
    }
    int j = beg;
    for (; j + 7 < end; j += 8) {
        int s[8]; float w[8]; u32 u[8];
#pragma unroll
        for (int k = 0; k < 8; ++k) s[k] = col[j + k];
#pragma unroll
        for (int k = 0; k < 8; ++k) {
            w[k] = dinv[s[k]];
            u[k] = act ? ((const u32*)(t + (size_t)s[k] * NCLS))[l] : 0u;
        }
#pragma unroll
        for (int k = 0; k < 8; ++k) {
            ax = fmaf(w[k], blo(u[k]), ax);
            ay = fmaf(w[k], bhi(u[k]), ay);
        }
    }
    for (; j < end; ++j) {
        int s0 = col[j];
        float w0 = dinv[s0];
        u32 u = act ? ((const u32*)(t + (size_t)s0 * NCLS))[l] : 0u;
        ax = fmaf(w0, blo(u), ax);
        ay = fmaf(w0, bhi(u), ay);
    }

    float v0 = -INFINITY, v1 = -INFINITY;
    if (act) {
        float2 bb = ((const float2*)bias)[l];
        v0 = fmaf(di, ax, bb.x);
        v1 = fmaf(di, ay, bb.y);
    }
    float m = fmaxf(v0, v1);
#pragma unroll
    for (int d = 16; d > 0; d >>= 1) m = fmaxf(m, __shfl_xor(m, d, 32));
    float e = act ? (expf(v0 - m) + expf(v1 - m)) : 0.f;
    float ssum = e;
#pragma unroll
    for (int d = 16; d > 0; d >>= 1) ssum += __shfl_xor(ssum, d, 32);
    float ls = logf(ssum);
    if (act) {
        float2 o; o.x = v0 - m - ls; o.y = v1 - m - ls;
        ((float2*)(out + (size_t)i * NCLS))[l] = o;
    }
}

// ---------------- launch ----------------

extern "C" void kernel_launch(void* const* d_in, const int* in_sizes, int n_in,
                              void* d_out, int out_size, void* d_ws, size_t ws_size,
                              hipStream_t stream) {
    const float* features = (const float*)d_in[0];
    const int* edge_index = (const int*)d_in[1];
    const float* W1 = (const float*)d_in[2];
    const float* b1 = (const float*)d_in[3];
    const float* gamma1 = (const float*)d_in[4];
    const float* beta1 = (const float*)d_in[5];
    const float* W2 = (const float*)d_in[6];
    const float* b2 = (const float*)d_in[7];
    const float* gamma2 = (const float*)d_in[8];
    const float* beta2 = (const float*)d_in[9];
    const float* W3 = (const float*)d_in[10];
    const float* b3 = (const float*)d_in[11];
    float* out = (float*)d_out;

    int n = in_sizes[0] / FEAT;
    int E = in_sizes[1] / 2;

    char* p = (char*)d_ws;
    auto alloc = [&](size_t bytes) -> void* {
        void* r = (void*)p;
        p += (bytes + 255) & ~(size_t)255;
        return r;
    };
    int* cnt     = (int*)alloc((size_t)n * 4);
    int* row_off = (int*)alloc((size_t)(n + 1) * 4);
    int* cursor  = (int*)alloc((size_t)n * 4);
    int* colb    = (int*)alloc((size_t)E * 4);
    int* bsum    = (int*)alloc(1024);
    int* boff    = (int*)alloc(1024);
    float* dinv  = (float*)alloc((size_t)n * 4);
    float* sums  = (float*)alloc(256 * 4);
    float* scale1 = (float*)alloc(128 * 4);
    float* shift1 = (float*)alloc(128 * 4);
    float* scale2 = (float*)alloc(128 * 4);
    float* shift2 = (float*)alloc(128 * 4);
    u16* hb      = (u16*)alloc((size_t)n * 128 * 2);   // transform output (bf16)
    u16* ab      = (u16*)alloc((size_t)n * 128 * 2);   // aggregated (bf16)

    const int* e_src = edge_index;
    const int* e_dst = edge_index + E;

    hipMemsetAsync(cnt, 0, (size_t)n * 4, stream);
    k_hist<<<(E + 255) / 256, 256, 0, stream>>>(e_dst, cnt, E);
    int nb = (n + 511) / 512;
    k_scan_a<<<nb, 256, 0, stream>>>(cnt, bsum, n);
    k_scan_b<<<1, 64, 0, stream>>>(bsum, boff, row_off, nb, n);
    k_scan_c<<<nb, 256, 0, stream>>>(cnt, boff, row_off, cursor, dinv, n);
    k_fill<<<(E + 255) / 256, 256, 0, stream>>>(e_src, e_dst, cursor, colb, E);

    int gb64 = (n + 63) / 64;
    int ngroups = (n + 7) / 8;
    int agggrid = 1024;

    // layer 1
    k_gemm128_f32<<<gb64, 256, 0, stream>>>(features, W1, hb, n);
    hipMemsetAsync(sums, 0, 256 * 4, stream);
    k_agg128<<<agggrid, 256, 0, stream>>>(hb, row_off, colb, dinv, b1, ab, sums, n, ngroups);
    k_bnfinal<<<1, 128, 0, stream>>>(sums, gamma1, beta1, scale1, shift1, n);

    // layer 2 (BN1+ReLU fused into GEMM2 input staging)
    k_gemm128_bf16<<<gb64, 256, 0, stream>>>(ab, W2, scale1, shift1, hb, n);
    hipMemsetAsync(sums, 0, 256 * 4, stream);
    k_agg128<<<agggrid, 256, 0, stream>>>(hb, row_off, colb, dinv, b2, ab, sums, n, ngroups);
    k_bnfinal<<<1, 128, 0, stream>>>(sums, gamma2, beta2, scale2, shift2, n);

    // layer 3: transform first, then 40-wide agg + log_softmax
    k_gemm40<<<(n + 255) / 256, 256, 0, stream>>>(ab, W3, scale2, shift2, hb, n);
    k_agg40<<<ngroups, 256, 0, stream>>>(hb, row_off, colb, dinv, b3, out, n);
}

// Round 5
// 417.226 us; speedup vs baseline: 1.4157x; 1.0465x over previous
//
#include <hip/hip_runtime.h>
#include <math.h>

#define FEAT 128
#define NCLS 40
#define BN_EPS 1e-5f

typedef unsigned short u16;
typedef unsigned int u32;

// bf16 helpers (RNE pack, exact unpack)
__device__ inline u32 f2b2(float a, float b) {
    u32 ua = __float_as_uint(a), ub = __float_as_uint(b);
    ua = (ua + 0x7fffu + ((ua >> 16) & 1u)) >> 16;
    ub = (ub + 0x7fffu + ((ub >> 16) & 1u)) >> 16;
    return ua | (ub << 16);
}
__device__ inline float b2f(u16 u) { return __uint_as_float((u32)u << 16); }
__device__ inline float4 b4fv(ushort4 u) {
    return make_float4(b2f(u.x), b2f(u.y), b2f(u.z), b2f(u.w));
}
__device__ inline float blo(u32 u) { return __uint_as_float(u << 16); }
__device__ inline float bhi(u32 u) { return __uint_as_float(u & 0xffff0000u); }

// accumulate 8 bf16 (uint4) * w into a[0..7]
__device__ inline void b8acc(uint4 u, float w, float* a) {
    a[0] = fmaf(w, blo(u.x), a[0]); a[1] = fmaf(w, bhi(u.x), a[1]);
    a[2] = fmaf(w, blo(u.y), a[2]); a[3] = fmaf(w, bhi(u.y), a[3]);
    a[4] = fmaf(w, blo(u.z), a[4]); a[5] = fmaf(w, bhi(u.z), a[5]);
    a[6] = fmaf(w, blo(u.w), a[6]); a[7] = fmaf(w, bhi(u.w), a[7]);
}

// ---------------- graph prep ----------------

__global__ void k_hist(const int* __restrict__ dst, int* __restrict__ cnt, int E) {
    int e = blockIdx.x * 256 + threadIdx.x;
    if (e < E) atomicAdd(&cnt[dst[e]], 1);
}

__global__ void k_scan_a(const int* __restrict__ cnt, int* __restrict__ bsum, int n) {
    int t = threadIdx.x;
    int idx = blockIdx.x * 512 + t * 2;
    int v = 0;
    if (idx < n) v += cnt[idx];
    if (idx + 1 < n) v += cnt[idx + 1];
    for (int d = 1; d < 64; d <<= 1) v += __shfl_xor(v, d, 64);
    __shared__ int ws[4];
    int lane = t & 63, w = t >> 6;
    if (lane == 0) ws[w] = v;
    __syncthreads();
    if (t == 0) bsum[blockIdx.x] = ws[0] + ws[1] + ws[2] + ws[3];
}

__global__ void k_scan_b(const int* __restrict__ bsum, int* __restrict__ boff,
                         int* __restrict__ row_off, int nb, int n) {
    if (threadIdx.x == 0) {
        int run = 0;
        for (int i = 0; i < nb; ++i) { boff[i] = run; run += bsum[i]; }
        row_off[n] = run;
    }
}

__global__ void k_scan_c(const int* __restrict__ cnt, const int* __restrict__ boff,
                         int* __restrict__ row_off, int* __restrict__ cursor,
                         float* __restrict__ dinv, int n) {
    int t = threadIdx.x;
    int idx = blockIdx.x * 512 + t * 2;
    int v0 = (idx < n) ? cnt[idx] : 0;
    int v1 = (idx + 1 < n) ? cnt[idx + 1] : 0;
    int s = v0 + v1;
    int lane = t & 63, w = t >> 6;
    int incl = s;
    for (int d = 1; d < 64; d <<= 1) {
        int o = __shfl_up(incl, d, 64);
        if (lane >= d) incl += o;
    }
    __shared__ int wsum[4];
    if (lane == 63) wsum[w] = incl;
    __syncthreads();
    int wpre = 0;
    for (int i = 0; i < w; ++i) wpre += wsum[i];
    int base = boff[blockIdx.x] + wpre + incl - s;
    if (idx < n) {
        row_off[idx] = base; cursor[idx] = base;
        dinv[idx] = rsqrtf((float)(v0 + 1));
    }
    if (idx + 1 < n) {
        row_off[idx + 1] = base + v0; cursor[idx + 1] = base + v0;
        dinv[idx + 1] = rsqrtf((float)(v1 + 1));
    }
}

// CSR fill: col only (4B scatter; adding more per-edge payload doubles dirty-line writeback)
__global__ void k_fill(const int* __restrict__ src, const int* __restrict__ dst,
                       int* __restrict__ cursor, int* __restrict__ col, int E) {
    int e = blockIdx.x * 256 + threadIdx.x;
    if (e < E) {
        int p = atomicAdd(&cursor[dst[e]], 1);
        col[p] = src[e];
    }
}

// linear pass: per-edge weight stream (linear write; dinv table is L2-resident)
__global__ void k_wsrc(const int* __restrict__ col, const float* __restrict__ dinv,
                       float* __restrict__ wsrc, int E) {
    int e = blockIdx.x * 256 + threadIdx.x;
    if (e < E) wsrc[e] = dinv[col[e]];
}

// ---------------- GEMM 128x128, fp32 X (layer 1), bf16 out ----------------

__global__ __launch_bounds__(256) void k_gemm128_f32(
    const float* __restrict__ X, const float* __restrict__ W,
    u16* __restrict__ Y, int M)
{
    __shared__ float Wsc[32 * 128];
    __shared__ float Xs[32 * 68];

    int t = threadIdx.x;
    int row0 = blockIdx.x * 64;
    int tx = t & 15, ty = t >> 4;

    float acc[4][8];
#pragma unroll
    for (int r = 0; r < 4; ++r)
#pragma unroll
        for (int c = 0; c < 8; ++c) acc[r][c] = 0.f;

    for (int k0 = 0; k0 < 128; k0 += 32) {
        __syncthreads();
        {
            const float4* W4 = (const float4*)(W + k0 * 128);
            float4* Ws4 = (float4*)Wsc;
#pragma unroll
            for (int i = 0; i < 4; ++i) Ws4[t + i * 256] = W4[t + i * 256];
        }
        {
            int rr = t >> 3;
            int kc = (t & 7) * 4;
#pragma unroll
            for (int p = 0; p < 2; ++p) {
                int r = rr + p * 32;
                int grow = row0 + r;
                float4 v = make_float4(0.f, 0.f, 0.f, 0.f);
                if (grow < M) v = *(const float4*)(X + (size_t)grow * 128 + k0 + kc);
                Xs[(kc + 0) * 68 + r] = v.x;
                Xs[(kc + 1) * 68 + r] = v.y;
                Xs[(kc + 2) * 68 + r] = v.z;
                Xs[(kc + 3) * 68 + r] = v.w;
            }
        }
        __syncthreads();
#pragma unroll 8
        for (int kk = 0; kk < 32; ++kk) {
            const float4 xv = *(const float4*)&Xs[kk * 68 + ty * 4];
            const float4 wa = *(const float4*)&Wsc[kk * 128 + tx * 8];
            const float4 wb = *(const float4*)&Wsc[kk * 128 + tx * 8 + 4];
            const float xr[4] = {xv.x, xv.y, xv.z, xv.w};
            const float wc[8] = {wa.x, wa.y, wa.z, wa.w, wb.x, wb.y, wb.z, wb.w};
#pragma unroll
            for (int r = 0; r < 4; ++r)
#pragma unroll
                for (int c = 0; c < 8; ++c)
                    acc[r][c] = fmaf(xr[r], wc[c], acc[r][c]);
        }
    }

#pragma unroll
    for (int r = 0; r < 4; ++r) {
        int grow = row0 + ty * 4 + r;
        if (grow < M) {
            uint4 o;
            o.x = f2b2(acc[r][0], acc[r][1]);
            o.y = f2b2(acc[r][2], acc[r][3]);
            o.z = f2b2(acc[r][4], acc[r][5]);
            o.w = f2b2(acc[r][6], acc[r][7]);
            *(uint4*)(Y + (size_t)grow * 128 + tx * 8) = o;
        }
    }
}

// ---------------- GEMM 128x128, bf16 X + fused BN+ReLU (layer 2), bf16 out ----------------

__global__ __launch_bounds__(256) void k_gemm128_bf16(
    const u16* __restrict__ X, const float* __restrict__ W,
    const float* __restrict__ scale, const float* __restrict__ shift,
    u16* __restrict__ Y, int M)
{
    __shared__ float Wsc[32 * 128];
    __shared__ float Xs[32 * 68];

    int t = threadIdx.x;
    int row0 = blockIdx.x * 64;
    int tx = t & 15, ty = t >> 4;

    float acc[4][8];
#pragma unroll
    for (int r = 0; r < 4; ++r)
#pragma unroll
        for (int c = 0; c < 8; ++c) acc[r][c] = 0.f;

    for (int k0 = 0; k0 < 128; k0 += 32) {
        __syncthreads();
        {
            const float4* W4 = (const float4*)(W + k0 * 128);
            float4* Ws4 = (float4*)Wsc;
#pragma unroll
            for (int i = 0; i < 4; ++i) Ws4[t + i * 256] = W4[t + i * 256];
        }
        {
            int rr = t >> 3;
            int kc = (t & 7) * 4;
            float4 sc = *(const float4*)(scale + k0 + kc);
            float4 sh = *(const float4*)(shift + k0 + kc);
#pragma unroll
            for (int p = 0; p < 2; ++p) {
                int r = rr + p * 32;
                int grow = row0 + r;
                float4 v = make_float4(0.f, 0.f, 0.f, 0.f);
                if (grow < M) v = b4fv(*(const ushort4*)(X + (size_t)grow * 128 + k0 + kc));
                v.x = fmaxf(fmaf(v.x, sc.x, sh.x), 0.f);
                v.y = fmaxf(fmaf(v.y, sc.y, sh.y), 0.f);
                v.z = fmaxf(fmaf(v.z, sc.z, sh.z), 0.f);
                v.w = fmaxf(fmaf(v.w, sc.w, sh.w), 0.f);
                Xs[(kc + 0) * 68 + r] = v.x;
                Xs[(kc + 1) * 68 + r] = v.y;
                Xs[(kc + 2) * 68 + r] = v.z;
                Xs[(kc + 3) * 68 + r] = v.w;
            }
        }
        __syncthreads();
#pragma unroll 8
        for (int kk = 0; kk < 32; ++kk) {
            const float4 xv = *(const float4*)&Xs[kk * 68 + ty * 4];
            const float4 wa = *(const float4*)&Wsc[kk * 128 + tx * 8];
            const float4 wb = *(const float4*)&Wsc[kk * 128 + tx * 8 + 4];
            const float xr[4] = {xv.x, xv.y, xv.z, xv.w};
            const float wc[8] = {wa.x, wa.y, wa.z, wa.w, wb.x, wb.y, wb.z, wb.w};
#pragma unroll
            for (int r = 0; r < 4; ++r)
#pragma unroll
                for (int c = 0; c < 8; ++c)
                    acc[r][c] = fmaf(xr[r], wc[c], acc[r][c]);
        }
    }

#pragma unroll
    for (int r = 0; r < 4; ++r) {
        int grow = row0 + ty * 4 + r;
        if (grow < M) {
            uint4 o;
            o.x = f2b2(acc[r][0], acc[r][1]);
            o.y = f2b2(acc[r][2], acc[r][3]);
            o.z = f2b2(acc[r][4], acc[r][5]);
            o.w = f2b2(acc[r][6], acc[r][7]);
            *(uint4*)(Y + (size_t)grow * 128 + tx * 8) = o;
        }
    }
}

// ---------------- GEMM 128->40, bf16 X + fused BN+ReLU, bf16 out ----------------

__global__ __launch_bounds__(256) void k_gemm40(
    const u16* __restrict__ X, const float* __restrict__ W,
    const float* __restrict__ scale, const float* __restrict__ shift,
    u16* __restrict__ Y, int M)
{
    __shared__ float Ws[128 * 40];
    __shared__ float Xs[32 * 260];

    int t = threadIdx.x;
    int row0 = blockIdx.x * 256;
    int tx = t & 3, ty = t >> 2;

    {
        const float4* W4 = (const float4*)W;
        float4* Ws4 = (float4*)Ws;
#pragma unroll
        for (int i = 0; i < 5; ++i) Ws4[t + i * 256] = W4[t + i * 256];
    }

    float acc[4][10];
#pragma unroll
    for (int r = 0; r < 4; ++r)
#pragma unroll
        for (int c = 0; c < 10; ++c) acc[r][c] = 0.f;

    for (int k0 = 0; k0 < 128; k0 += 32) {
        __syncthreads();
        {
            int rr = t >> 3;
            int kc = (t & 7) * 4;
            float4 sc = *(const float4*)(scale + k0 + kc);
            float4 sh = *(const float4*)(shift + k0 + kc);
#pragma unroll
            for (int p = 0; p < 8; ++p) {
                int r = rr + p * 32;
                int grow = row0 + r;
                float4 v = make_float4(0.f, 0.f, 0.f, 0.f);
                if (grow < M) v = b4fv(*(const ushort4*)(X + (size_t)grow * 128 + k0 + kc));
                v.x = fmaxf(fmaf(v.x, sc.x, sh.x), 0.f);
                v.y = fmaxf(fmaf(v.y, sc.y, sh.y), 0.f);
                v.z = fmaxf(fmaf(v.z, sc.z, sh.z), 0.f);
                v.w = fmaxf(fmaf(v.w, sc.w, sh.w), 0.f);
                Xs[(kc + 0) * 260 + r] = v.x;
                Xs[(kc + 1) * 260 + r] = v.y;
                Xs[(kc + 2) * 260 + r] = v.z;
                Xs[(kc + 3) * 260 + r] = v.w;
            }
        }
        __syncthreads();
#pragma unroll 8
        for (int kk = 0; kk < 32; ++kk) {
            const float4 xv = *(const float4*)&Xs[kk * 260 + ty * 4];
            const float xr[4] = {xv.x, xv.y, xv.z, xv.w};
            float wc[10];
#pragma unroll
            for (int c = 0; c < 5; ++c) {
                float2 w2 = *(const float2*)&Ws[(k0 + kk) * 40 + tx * 10 + c * 2];
                wc[c * 2] = w2.x; wc[c * 2 + 1] = w2.y;
            }
#pragma unroll
            for (int r = 0; r < 4; ++r)
#pragma unroll
                for (int c = 0; c < 10; ++c)
                    acc[r][c] = fmaf(xr[r], wc[c], acc[r][c]);
        }
    }

#pragma unroll
    for (int r = 0; r < 4; ++r) {
        int grow = row0 + ty * 4 + r;
        if (grow < M) {
            u32* yp = (u32*)(Y + (size_t)grow * 40 + tx * 10);
#pragma unroll
            for (int c = 0; c < 5; ++c)
                yp[c] = f2b2(acc[r][c * 2], acc[r][c * 2 + 1]);
        }
    }
}

// ---------------- aggregation 128-wide (bf16 src, fp32 accum, bf16 out) ----------------
// 16 lanes/node, uint4 (8 bf16, 16 B) per lane -> one vmem instr per gathered row
// per 16 lanes. 16 nodes/block, one node-group per block (full HW rebalancing).

__global__ __launch_bounds__(256) void k_agg128(
    const u16* __restrict__ t, const int* __restrict__ roff,
    const int* __restrict__ col, const float* __restrict__ wsrc,
    const float* __restrict__ dinv, const float* __restrict__ bias,
    u16* __restrict__ out, int n)
{
    int wid = threadIdx.x >> 4;
    int lane = threadIdx.x & 15;
    int i = blockIdx.x * 16 + wid;
    if (i >= n) return;
    int beg = roff[i], end = roff[i + 1];
    float di = dinv[i];

    float a[8];
    {
        uint4 su = ((const uint4*)(t + (size_t)i * 128))[lane];
        a[0] = di * blo(su.x); a[1] = di * bhi(su.x);
        a[2] = di * blo(su.y); a[3] = di * bhi(su.y);
        a[4] = di * blo(su.z); a[5] = di * bhi(su.z);
        a[6] = di * blo(su.w); a[7] = di * bhi(su.w);
    }

    int j = beg;
    for (; j + 7 < end; j += 8) {
        int s[8]; float w[8]; uint4 v[8];
#pragma unroll
        for (int k = 0; k < 8; ++k) { s[k] = col[j + k]; w[k] = wsrc[j + k]; }
#pragma unroll
        for (int k = 0; k < 8; ++k) v[k] = ((const uint4*)(t + (size_t)s[k] * 128))[lane];
#pragma unroll
        for (int k = 0; k < 8; ++k) b8acc(v[k], w[k], a);
    }
    for (; j < end; ++j) {
        float w0 = wsrc[j];
        uint4 v = ((const uint4*)(t + (size_t)col[j] * 128))[lane];
        b8acc(v, w0, a);
    }

    float4 bA = ((const float4*)bias)[lane * 2];
    float4 bB = ((const float4*)bias)[lane * 2 + 1];
    uint4 o;
    o.x = f2b2(fmaf(di, a[0], bA.x), fmaf(di, a[1], bA.y));
    o.y = f2b2(fmaf(di, a[2], bA.z), fmaf(di, a[3], bA.w));
    o.z = f2b2(fmaf(di, a[4], bB.x), fmaf(di, a[5], bB.y));
    o.w = f2b2(fmaf(di, a[6], bB.z), fmaf(di, a[7], bB.w));
    ((uint4*)(out + (size_t)i * 128))[lane] = o;
}

// ---------------- BN stats (vectorized): 16 row-threads x 16 feature-lanes ----------------

__global__ __launch_bounds__(256) void k_bnstats(const u16* __restrict__ a,
                                                 float* __restrict__ sums, int n) {
    int lane = threadIdx.x & 15;   // feature block: feats [lane*8, lane*8+8)
    int rt = threadIdx.x >> 4;     // row thread
    float s[8], q[8];
#pragma unroll
    for (int k = 0; k < 8; ++k) { s[k] = 0.f; q[k] = 0.f; }

    for (int i = blockIdx.x * 16 + rt; i < n; i += gridDim.x * 16) {
        uint4 u = ((const uint4*)(a + (size_t)i * 128))[lane];
        float v[8] = {blo(u.x), bhi(u.x), blo(u.y), bhi(u.y),
                      blo(u.z), bhi(u.z), blo(u.w), bhi(u.w)};
#pragma unroll
        for (int k = 0; k < 8; ++k) { s[k] += v[k]; q[k] = fmaf(v[k], v[k], q[k]); }
    }

    __shared__ float red[16][128];
#pragma unroll
    for (int k = 0; k < 8; ++k) red[rt][lane * 8 + k] = s[k];
    __syncthreads();
    if (threadIdx.x < 128) {
        float v = 0.f;
#pragma unroll
        for (int w = 0; w < 16; ++w) v += red[w][threadIdx.x];
        atomicAdd(&sums[threadIdx.x], v);
    }
    __syncthreads();
#pragma unroll
    for (int k = 0; k < 8; ++k) red[rt][lane * 8 + k] = q[k];
    __syncthreads();
    if (threadIdx.x < 128) {
        float v = 0.f;
#pragma unroll
        for (int w = 0; w < 16; ++w) v += red[w][threadIdx.x];
        atomicAdd(&sums[128 + threadIdx.x], v);
    }
}

__global__ void k_bnfinal(const float* __restrict__ sums, const float* __restrict__ gamma,
                          const float* __restrict__ beta, float* __restrict__ scale,
                          float* __restrict__ shift, int n) {
    int f = threadIdx.x;
    float inv_n = 1.f / (float)n;
    float mu = sums[f] * inv_n;
    float var = sums[128 + f] * inv_n - mu * mu;
    float rs = rsqrtf(var + BN_EPS);
    float sc = gamma[f] * rs;
    scale[f] = sc;
    shift[f] = beta[f] - mu * sc;
}

// ---------------- final: 40-wide agg (bf16 src) + bias + log_softmax ----------------
// 2 nodes per wave: 32-lane groups, lanes 0..19 hold classes {2l, 2l+1} as one u32.

__global__ __launch_bounds__(256) void k_agg40(
    const u16* __restrict__ t, const int* __restrict__ roff,
    const int* __restrict__ col, const float* __restrict__ wsrc,
    const float* __restrict__ dinv, const float* __restrict__ bias,
    float* __restrict__ out, int n)
{
    int i = blockIdx.x * 8 + (threadIdx.x >> 5);
    if (i >= n) return;
    int l = threadIdx.x & 31;
    bool act = l < 20;
    int beg = roff[i], end = roff[i + 1];
    float di = dinv[i];

    float ax = 0.f, ay = 0.f;
    if (act) {
        u32 u = ((const u32*)(t + (size_t)i * NCLS))[l];
        ax = di * blo(u); ay = di * bhi(u);
    }
    int j = beg;
    for (; j + 7 < end; j += 8) {
        int s[8]; float w[8]; u32 u[8];
#pragma unroll
        for (int k = 0; k < 8; ++k) { s[k] = col[j + k]; w[k] = wsrc[j + k]; }
#pragma unroll
        for (int k = 0; k < 8; ++k)
            u[k] = act ? ((const u32*)(t + (size_t)s[k] * NCLS))[l] : 0u;
#pragma unroll
        for (int k = 0; k < 8; ++k) {
            ax = fmaf(w[k], blo(u[k]), ax);
            ay = fmaf(w[k], bhi(u[k]), ay);
        }
    }
    for (; j < end; ++j) {
        float w0 = wsrc[j];
        u32 u = act ? ((const u32*)(t + (size_t)col[j] * NCLS))[l] : 0u;
        ax = fmaf(w0, blo(u), ax);
        ay = fmaf(w0, bhi(u), ay);
    }

    float v0 = -INFINITY, v1 = -INFINITY;
    if (act) {
        float2 bb = ((const float2*)bias)[l];
        v0 = fmaf(di, ax, bb.x);
        v1 = fmaf(di, ay, bb.y);
    }
    float m = fmaxf(v0, v1);
#pragma unroll
    for (int d = 16; d > 0; d >>= 1) m = fmaxf(m, __shfl_xor(m, d, 32));
    float e = act ? (expf(v0 - m) + expf(v1 - m)) : 0.f;
    float ssum = e;
#pragma unroll
    for (int d = 16; d > 0; d >>= 1) ssum += __shfl_xor(ssum, d, 32);
    float ls = logf(ssum);
    if (act) {
        float2 o; o.x = v0 - m - ls; o.y = v1 - m - ls;
        ((float2*)(out + (size_t)i * NCLS))[l] = o;
    }
}

// ---------------- launch ----------------

extern "C" void kernel_launch(void* const* d_in, const int* in_sizes, int n_in,
                              void* d_out, int out_size, void* d_ws, size_t ws_size,
                              hipStream_t stream) {
    const float* features = (const float*)d_in[0];
    const int* edge_index = (const int*)d_in[1];
    const float* W1 = (const float*)d_in[2];
    const float* b1 = (const float*)d_in[3];
    const float* gamma1 = (const float*)d_in[4];
    const float* beta1 = (const float*)d_in[5];
    const float* W2 = (const float*)d_in[6];
    const float* b2 = (const float*)d_in[7];
    const float* gamma2 = (const float*)d_in[8];
    const float* beta2 = (const float*)d_in[9];
    const float* W3 = (const float*)d_in[10];
    const float* b3 = (const float*)d_in[11];
    float* out = (float*)d_out;

    int n = in_sizes[0] / FEAT;
    int E = in_sizes[1] / 2;

    char* p = (char*)d_ws;
    auto alloc = [&](size_t bytes) -> void* {
        void* r = (void*)p;
        p += (bytes + 255) & ~(size_t)255;
        return r;
    };
    int* cnt     = (int*)alloc((size_t)n * 4);
    int* row_off = (int*)alloc((size_t)(n + 1) * 4);
    int* cursor  = (int*)alloc((size_t)n * 4);
    int* colb    = (int*)alloc((size_t)E * 4);
    float* wsrc  = (float*)alloc((size_t)E * 4);
    int* bsum    = (int*)alloc(1024);
    int* boff    = (int*)alloc(1024);
    float* dinv  = (float*)alloc((size_t)n * 4);
    float* sums  = (float*)alloc(256 * 4);
    float* scale1 = (float*)alloc(128 * 4);
    float* shift1 = (float*)alloc(128 * 4);
    float* scale2 = (float*)alloc(128 * 4);
    float* shift2 = (float*)alloc(128 * 4);
    u16* hb      = (u16*)alloc((size_t)n * 128 * 2);   // transform output (bf16)
    u16* ab      = (u16*)alloc((size_t)n * 128 * 2);   // aggregated (bf16)

    const int* e_src = edge_index;
    const int* e_dst = edge_index + E;

    hipMemsetAsync(cnt, 0, (size_t)n * 4, stream);
    k_hist<<<(E + 255) / 256, 256, 0, stream>>>(e_dst, cnt, E);
    int nb = (n + 511) / 512;
    k_scan_a<<<nb, 256, 0, stream>>>(cnt, bsum, n);
    k_scan_b<<<1, 64, 0, stream>>>(bsum, boff, row_off, nb, n);
    k_scan_c<<<nb, 256, 0, stream>>>(cnt, boff, row_off, cursor, dinv, n);
    k_fill<<<(E + 255) / 256, 256, 0, stream>>>(e_src, e_dst, cursor, colb, E);
    k_wsrc<<<(E + 255) / 256, 256, 0, stream>>>(colb, dinv, wsrc, E);

    int gb64 = (n + 63) / 64;
    int gb16 = (n + 15) / 16;
    int gb8 = (n + 7) / 8;

    // layer 1
    k_gemm128_f32<<<gb64, 256, 0, stream>>>(features, W1, hb, n);
    k_agg128<<<gb16, 256, 0, stream>>>(hb, row_off, colb, wsrc, dinv, b1, ab, n);
    hipMemsetAsync(sums, 0, 256 * 4, stream);
    k_bnstats<<<512, 256, 0, stream>>>(ab, sums, n);
    k_bnfinal<<<1, 128, 0, stream>>>(sums, gamma1, beta1, scale1, shift1, n);

    // layer 2 (BN1+ReLU fused into GEMM2 input staging)
    k_gemm128_bf16<<<gb64, 256, 0, stream>>>(ab, W2, scale1, shift1, hb, n);
    k_agg128<<<gb16, 256, 0, stream>>>(hb, row_off, colb, wsrc, dinv, b2, ab, n);
    hipMemsetAsync(sums, 0, 256 * 4, stream);
    k_bnstats<<<512, 256, 0, stream>>>(ab, sums, n);
    k_bnfinal<<<1, 128, 0, stream>>>(sums, gamma2, beta2, scale2, shift2, n);

    // layer 3: transform first, then 40-wide agg + log_softmax
    k_gemm40<<<(n + 255) / 256, 256, 0, stream>>>(ab, W3, scale2, shift2, hb, n);
    k_agg40<<<gb8, 256, 0, stream>>>(hb, row_off, colb, wsrc, dinv, b3, out, n);
}

// Round 6
// 411.974 us; speedup vs baseline: 1.4338x; 1.0127x over previous
//
#include <hip/hip_runtime.h>
#include <math.h>

#define FEAT 128
#define NCLS 40
#define BN_EPS 1e-5f

typedef unsigned short u16;
typedef unsigned int u32;

// bf16 helpers (RNE pack, exact unpack)
__device__ inline u32 f2b2(float a, float b) {
    u32 ua = __float_as_uint(a), ub = __float_as_uint(b);
    ua = (ua + 0x7fffu + ((ua >> 16) & 1u)) >> 16;
    ub = (ub + 0x7fffu + ((ub >> 16) & 1u)) >> 16;
    return ua | (ub << 16);
}
__device__ inline float b2f(u16 u) { return __uint_as_float((u32)u << 16); }
__device__ inline float4 b4fv(ushort4 u) {
    return make_float4(b2f(u.x), b2f(u.y), b2f(u.z), b2f(u.w));
}
__device__ inline float blo(u32 u) { return __uint_as_float(u << 16); }
__device__ inline float bhi(u32 u) { return __uint_as_float(u & 0xffff0000u); }

// accumulate 8 bf16 (uint4) * w into a[0..7]
__device__ inline void b8acc(uint4 u, float w, float* a) {
    a[0] = fmaf(w, blo(u.x), a[0]); a[1] = fmaf(w, bhi(u.x), a[1]);
    a[2] = fmaf(w, blo(u.y), a[2]); a[3] = fmaf(w, bhi(u.y), a[3]);
    a[4] = fmaf(w, blo(u.z), a[4]); a[5] = fmaf(w, bhi(u.z), a[5]);
    a[6] = fmaf(w, blo(u.w), a[6]); a[7] = fmaf(w, bhi(u.w), a[7]);
}

// ---------------- graph prep ----------------

__global__ void k_hist(const int* __restrict__ dst, int* __restrict__ cnt, int E) {
    int e = blockIdx.x * 256 + threadIdx.x;
    if (e < E) atomicAdd(&cnt[dst[e]], 1);
}

__global__ void k_scan_a(const int* __restrict__ cnt, int* __restrict__ bsum, int n) {
    int t = threadIdx.x;
    int idx = blockIdx.x * 512 + t * 2;
    int v = 0;
    if (idx < n) v += cnt[idx];
    if (idx + 1 < n) v += cnt[idx + 1];
    for (int d = 1; d < 64; d <<= 1) v += __shfl_xor(v, d, 64);
    __shared__ int ws[4];
    int lane = t & 63, w = t >> 6;
    if (lane == 0) ws[w] = v;
    __syncthreads();
    if (t == 0) bsum[blockIdx.x] = ws[0] + ws[1] + ws[2] + ws[3];
}

__global__ void k_scan_b(const int* __restrict__ bsum, int* __restrict__ boff,
                         int* __restrict__ row_off, int nb, int n) {
    if (threadIdx.x == 0) {
        int run = 0;
        for (int i = 0; i < nb; ++i) { boff[i] = run; run += bsum[i]; }
        row_off[n] = run;
    }
}

__global__ void k_scan_c(const int* __restrict__ cnt, const int* __restrict__ boff,
                         int* __restrict__ row_off, int* __restrict__ cursor,
                         float* __restrict__ dinv, int n) {
    int t = threadIdx.x;
    int idx = blockIdx.x * 512 + t * 2;
    int v0 = (idx < n) ? cnt[idx] : 0;
    int v1 = (idx + 1 < n) ? cnt[idx + 1] : 0;
    int s = v0 + v1;
    int lane = t & 63, w = t >> 6;
    int incl = s;
    for (int d = 1; d < 64; d <<= 1) {
        int o = __shfl_up(incl, d, 64);
        if (lane >= d) incl += o;
    }
    __shared__ int wsum[4];
    if (lane == 63) wsum[w] = incl;
    __syncthreads();
    int wpre = 0;
    for (int i = 0; i < w; ++i) wpre += wsum[i];
    int base = boff[blockIdx.x] + wpre + incl - s;
    if (idx < n) {
        row_off[idx] = base; cursor[idx] = base;
        dinv[idx] = rsqrtf((float)(v0 + 1));
    }
    if (idx + 1 < n) {
        row_off[idx + 1] = base + v0; cursor[idx + 1] = base + v0;
        dinv[idx + 1] = rsqrtf((float)(v1 + 1));
    }
}

// XCD-partitioned CSR fill: block b owns dst range (b&7), edge chunk (b>>3).
// With round-robin blockIdx->XCD dispatch, each col partition (~400 KB) is
// written by ONE XCD -> scatter lines dirty once in one L2 (WRITE ~3 MB
// instead of 52 MB of cross-XCD partial-line writeback). Costs 8x streaming
// re-read of the edge list (~51 MB @ ~6 TB/s ~ 9 us).
__global__ __launch_bounds__(256) void k_fill(
    const int* __restrict__ src, const int* __restrict__ dst,
    int* __restrict__ cursor, int* __restrict__ col, int E, int n, int nchunks)
{
    int part = blockIdx.x & 7;
    int chunk = blockIdx.x >> 3;
    int lo = (int)(((long long)n * part) >> 3);
    int hi = (int)(((long long)n * (part + 1)) >> 3);
    int per = (E + nchunks - 1) / nchunks;
    int e0 = chunk * per;
    int e1 = e0 + per; if (e1 > E) e1 = E;
    for (int e = e0 + threadIdx.x; e < e1; e += 256) {
        int d = dst[e];
        if (d >= lo && d < hi) {
            int p = atomicAdd(&cursor[d], 1);
            col[p] = src[e];
        }
    }
}

// linear pass: per-edge weight stream (linear write; dinv table is L2-resident)
__global__ void k_wsrc(const int* __restrict__ col, const float* __restrict__ dinv,
                       float* __restrict__ wsrc, int E) {
    int e = blockIdx.x * 256 + threadIdx.x;
    if (e < E) wsrc[e] = dinv[col[e]];
}

// ---------------- GEMM 128x128, fp32 X (layer 1), bf16 out ----------------

__global__ __launch_bounds__(256) void k_gemm128_f32(
    const float* __restrict__ X, const float* __restrict__ W,
    u16* __restrict__ Y, int M)
{
    __shared__ float Wsc[32 * 128];
    __shared__ float Xs[32 * 68];

    int t = threadIdx.x;
    int row0 = blockIdx.x * 64;
    int tx = t & 15, ty = t >> 4;

    float acc[4][8];
#pragma unroll
    for (int r = 0; r < 4; ++r)
#pragma unroll
        for (int c = 0; c < 8; ++c) acc[r][c] = 0.f;

    for (int k0 = 0; k0 < 128; k0 += 32) {
        __syncthreads();
        {
            const float4* W4 = (const float4*)(W + k0 * 128);
            float4* Ws4 = (float4*)Wsc;
#pragma unroll
            for (int i = 0; i < 4; ++i) Ws4[t + i * 256] = W4[t + i * 256];
        }
        {
            int rr = t >> 3;
            int kc = (t & 7) * 4;
#pragma unroll
            for (int p = 0; p < 2; ++p) {
                int r = rr + p * 32;
                int grow = row0 + r;
                float4 v = make_float4(0.f, 0.f, 0.f, 0.f);
                if (grow < M) v = *(const float4*)(X + (size_t)grow * 128 + k0 + kc);
                Xs[(kc + 0) * 68 + r] = v.x;
                Xs[(kc + 1) * 68 + r] = v.y;
                Xs[(kc + 2) * 68 + r] = v.z;
                Xs[(kc + 3) * 68 + r] = v.w;
            }
        }
        __syncthreads();
#pragma unroll 8
        for (int kk = 0; kk < 32; ++kk) {
            const float4 xv = *(const float4*)&Xs[kk * 68 + ty * 4];
            const float4 wa = *(const float4*)&Wsc[kk * 128 + tx * 8];
            const float4 wb = *(const float4*)&Wsc[kk * 128 + tx * 8 + 4];
            const float xr[4] = {xv.x, xv.y, xv.z, xv.w};
            const float wc[8] = {wa.x, wa.y, wa.z, wa.w, wb.x, wb.y, wb.z, wb.w};
#pragma unroll
            for (int r = 0; r < 4; ++r)
#pragma unroll
                for (int c = 0; c < 8; ++c)
                    acc[r][c] = fmaf(xr[r], wc[c], acc[r][c]);
        }
    }

#pragma unroll
    for (int r = 0; r < 4; ++r) {
        int grow = row0 + ty * 4 + r;
        if (grow < M) {
            uint4 o;
            o.x = f2b2(acc[r][0], acc[r][1]);
            o.y = f2b2(acc[r][2], acc[r][3]);
            o.z = f2b2(acc[r][4], acc[r][5]);
            o.w = f2b2(acc[r][6], acc[r][7]);
            *(uint4*)(Y + (size_t)grow * 128 + tx * 8) = o;
        }
    }
}

// ---------------- GEMM 128x128, bf16 X + fused BN+ReLU (layer 2), bf16 out ----------------

__global__ __launch_bounds__(256) void k_gemm128_bf16(
    const u16* __restrict__ X, const float* __restrict__ W,
    const float* __restrict__ scale, const float* __restrict__ shift,
    u16* __restrict__ Y, int M)
{
    __shared__ float Wsc[32 * 128];
    __shared__ float Xs[32 * 68];

    int t = threadIdx.x;
    int row0 = blockIdx.x * 64;
    int tx = t & 15, ty = t >> 4;

    float acc[4][8];
#pragma unroll
    for (int r = 0; r < 4; ++r)
#pragma unroll
        for (int c = 0; c < 8; ++c) acc[r][c] = 0.f;

    for (int k0 = 0; k0 < 128; k0 += 32) {
        __syncthreads();
        {
            const float4* W4 = (const float4*)(W + k0 * 128);
            float4* Ws4 = (float4*)Wsc;
#pragma unroll
            for (int i = 0; i < 4; ++i) Ws4[t + i * 256] = W4[t + i * 256];
        }
        {
            int rr = t >> 3;
            int kc = (t & 7) * 4;
            float4 sc = *(const float4*)(scale + k0 + kc);
            float4 sh = *(const float4*)(shift + k0 + kc);
#pragma unroll
            for (int p = 0; p < 2; ++p) {
                int r = rr + p * 32;
                int grow = row0 + r;
                float4 v = make_float4(0.f, 0.f, 0.f, 0.f);
                if (grow < M) v = b4fv(*(const ushort4*)(X + (size_t)grow * 128 + k0 + kc));
                v.x = fmaxf(fmaf(v.x, sc.x, sh.x), 0.f);
                v.y = fmaxf(fmaf(v.y, sc.y, sh.y), 0.f);
                v.z = fmaxf(fmaf(v.z, sc.z, sh.z), 0.f);
                v.w = fmaxf(fmaf(v.w, sc.w, sh.w), 0.f);
                Xs[(kc + 0) * 68 + r] = v.x;
                Xs[(kc + 1) * 68 + r] = v.y;
                Xs[(kc + 2) * 68 + r] = v.z;
                Xs[(kc + 3) * 68 + r] = v.w;
            }
        }
        __syncthreads();
#pragma unroll 8
        for (int kk = 0; kk < 32; ++kk) {
            const float4 xv = *(const float4*)&Xs[kk * 68 + ty * 4];
            const float4 wa = *(const float4*)&Wsc[kk * 128 + tx * 8];
            const float4 wb = *(const float4*)&Wsc[kk * 128 + tx * 8 + 4];
            const float xr[4] = {xv.x, xv.y, xv.z, xv.w};
            const float wc[8] = {wa.x, wa.y, wa.z, wa.w, wb.x, wb.y, wb.z, wb.w};
#pragma unroll
            for (int r = 0; r < 4; ++r)
#pragma unroll
                for (int c = 0; c < 8; ++c)
                    acc[r][c] = fmaf(xr[r], wc[c], acc[r][c]);
        }
    }

#pragma unroll
    for (int r = 0; r < 4; ++r) {
        int grow = row0 + ty * 4 + r;
        if (grow < M) {
            uint4 o;
            o.x = f2b2(acc[r][0], acc[r][1]);
            o.y = f2b2(acc[r][2], acc[r][3]);
            o.z = f2b2(acc[r][4], acc[r][5]);
            o.w = f2b2(acc[r][6], acc[r][7]);
            *(uint4*)(Y + (size_t)grow * 128 + tx * 8) = o;
        }
    }
}

// ---------------- GEMM 128->40, bf16 X + fused BN+ReLU, bf16 out ----------------

__global__ __launch_bounds__(256) void k_gemm40(
    const u16* __restrict__ X, const float* __restrict__ W,
    const float* __restrict__ scale, const float* __restrict__ shift,
    u16* __restrict__ Y, int M)
{
    __shared__ float Ws[128 * 40];
    __shared__ float Xs[32 * 260];

    int t = threadIdx.x;
    int row0 = blockIdx.x * 256;
    int tx = t & 3, ty = t >> 2;

    {
        const float4* W4 = (const float4*)W;
        float4* Ws4 = (float4*)Ws;
#pragma unroll
        for (int i = 0; i < 5; ++i) Ws4[t + i * 256] = W4[t + i * 256];
    }

    float acc[4][10];
#pragma unroll
    for (int r = 0; r < 4; ++r)
#pragma unroll
        for (int c = 0; c < 10; ++c) acc[r][c] = 0.f;

    for (int k0 = 0; k0 < 128; k0 += 32) {
        __syncthreads();
        {
            int rr = t >> 3;
            int kc = (t & 7) * 4;
            float4 sc = *(const float4*)(scale + k0 + kc);
            float4 sh = *(const float4*)(shift + k0 + kc);
#pragma unroll
            for (int p = 0; p < 8; ++p) {
                int r = rr + p * 32;
                int grow = row0 + r;
                float4 v = make_float4(0.f, 0.f, 0.f, 0.f);
                if (grow < M) v = b4fv(*(const ushort4*)(X + (size_t)grow * 128 + k0 + kc));
                v.x = fmaxf(fmaf(v.x, sc.x, sh.x), 0.f);
                v.y = fmaxf(fmaf(v.y, sc.y, sh.y), 0.f);
                v.z = fmaxf(fmaf(v.z, sc.z, sh.z), 0.f);
                v.w = fmaxf(fmaf(v.w, sc.w, sh.w), 0.f);
                Xs[(kc + 0) * 260 + r] = v.x;
                Xs[(kc + 1) * 260 + r] = v.y;
                Xs[(kc + 2) * 260 + r] = v.z;
                Xs[(kc + 3) * 260 + r] = v.w;
            }
        }
        __syncthreads();
#pragma unroll 8
        for (int kk = 0; kk < 32; ++kk) {
            const float4 xv = *(const float4*)&Xs[kk * 260 + ty * 4];
            const float xr[4] = {xv.x, xv.y, xv.z, xv.w};
            float wc[10];
#pragma unroll
            for (int c = 0; c < 5; ++c) {
                float2 w2 = *(const float2*)&Ws[(k0 + kk) * 40 + tx * 10 + c * 2];
                wc[c * 2] = w2.x; wc[c * 2 + 1] = w2.y;
            }
#pragma unroll
            for (int r = 0; r < 4; ++r)
#pragma unroll
                for (int c = 0; c < 10; ++c)
                    acc[r][c] = fmaf(xr[r], wc[c], acc[r][c]);
        }
    }

#pragma unroll
    for (int r = 0; r < 4; ++r) {
        int grow = row0 + ty * 4 + r;
        if (grow < M) {
            u32* yp = (u32*)(Y + (size_t)grow * 40 + tx * 10);
#pragma unroll
            for (int c = 0; c < 5; ++c)
                yp[c] = f2b2(acc[r][c * 2], acc[r][c * 2 + 1]);
        }
    }
}

// ---------------- aggregation 128-wide (bf16 src, fp32 accum, bf16 out) ----------------
// 16 lanes/node, uint4 (8 bf16, 16 B) per lane; 16 nodes/block.

__global__ __launch_bounds__(256) void k_agg128(
    const u16* __restrict__ t, const int* __restrict__ roff,
    const int* __restrict__ col, const float* __restrict__ wsrc,
    const float* __restrict__ dinv, const float* __restrict__ bias,
    u16* __restrict__ out, int n)
{
    int wid = threadIdx.x >> 4;
    int lane = threadIdx.x & 15;
    int i = blockIdx.x * 16 + wid;
    if (i >= n) return;
    int beg = roff[i], end = roff[i + 1];
    float di = dinv[i];

    float a[8];
    {
        uint4 su = ((const uint4*)(t + (size_t)i * 128))[lane];
        a[0] = di * blo(su.x); a[1] = di * bhi(su.x);
        a[2] = di * blo(su.y); a[3] = di * bhi(su.y);
        a[4] = di * blo(su.z); a[5] = di * bhi(su.z);
        a[6] = di * blo(su.w); a[7] = di * bhi(su.w);
    }

    int j = beg;
    for (; j + 7 < end; j += 8) {
        int s[8]; float w[8]; uint4 v[8];
#pragma unroll
        for (int k = 0; k < 8; ++k) { s[k] = col[j + k]; w[k] = wsrc[j + k]; }
#pragma unroll
        for (int k = 0; k < 8; ++k) v[k] = ((const uint4*)(t + (size_t)s[k] * 128))[lane];
#pragma unroll
        for (int k = 0; k < 8; ++k) b8acc(v[k], w[k], a);
    }
    for (; j < end; ++j) {
        float w0 = wsrc[j];
        uint4 v = ((const uint4*)(t + (size_t)col[j] * 128))[lane];
        b8acc(v, w0, a);
    }

    float4 bA = ((const float4*)bias)[lane * 2];
    float4 bB = ((const float4*)bias)[lane * 2 + 1];
    uint4 o;
    o.x = f2b2(fmaf(di, a[0], bA.x), fmaf(di, a[1], bA.y));
    o.y = f2b2(fmaf(di, a[2], bA.z), fmaf(di, a[3], bA.w));
    o.z = f2b2(fmaf(di, a[4], bB.x), fmaf(di, a[5], bB.y));
    o.w = f2b2(fmaf(di, a[6], bB.z), fmaf(di, a[7], bB.w));
    ((uint4*)(out + (size_t)i * 128))[lane] = o;
}

// ---------------- BN stats (vectorized): 16 row-threads x 16 feature-lanes ----------------

__global__ __launch_bounds__(256) void k_bnstats(const u16* __restrict__ a,
                                                 float* __restrict__ sums, int n) {
    int lane = threadIdx.x & 15;   // feature block: feats [lane*8, lane*8+8)
    int rt = threadIdx.x >> 4;     // row thread
    float s[8], q[8];
#pragma unroll
    for (int k = 0; k < 8; ++k) { s[k] = 0.f; q[k] = 0.f; }

    for (int i = blockIdx.x * 16 + rt; i < n; i += gridDim.x * 16) {
        uint4 u = ((const uint4*)(a + (size_t)i * 128))[lane];
        float v[8] = {blo(u.x), bhi(u.x), blo(u.y), bhi(u.y),
                      blo(u.z), bhi(u.z), blo(u.w), bhi(u.w)};
#pragma unroll
        for (int k = 0; k < 8; ++k) { s[k] += v[k]; q[k] = fmaf(v[k], v[k], q[k]); }
    }

    __shared__ float red[16][128];
#pragma unroll
    for (int k = 0; k < 8; ++k) red[rt][lane * 8 + k] = s[k];
    __syncthreads();
    if (threadIdx.x < 128) {
        float v = 0.f;
#pragma unroll
        for (int w = 0; w < 16; ++w) v += red[w][threadIdx.x];
        atomicAdd(&sums[threadIdx.x], v);
    }
    __syncthreads();
#pragma unroll
    for (int k = 0; k < 8; ++k) red[rt][lane * 8 + k] = q[k];
    __syncthreads();
    if (threadIdx.x < 128) {
        float v = 0.f;
#pragma unroll
        for (int w = 0; w < 16; ++w) v += red[w][threadIdx.x];
        atomicAdd(&sums[128 + threadIdx.x], v);
    }
}

__global__ void k_bnfinal(const float* __restrict__ sums, const float* __restrict__ gamma,
                          const float* __restrict__ beta, float* __restrict__ scale,
                          float* __restrict__ shift, int n) {
    int f = threadIdx.x;
    float inv_n = 1.f / (float)n;
    float mu = sums[f] * inv_n;
    float var = sums[128 + f] * inv_n - mu * mu;
    float rs = rsqrtf(var + BN_EPS);
    float sc = gamma[f] * rs;
    scale[f] = sc;
    shift[f] = beta[f] - mu * sc;
}

// ---------------- final: 40-wide agg (bf16 src) + bias + log_softmax ----------------
// 2 nodes per wave: 32-lane groups, lanes 0..19 hold classes {2l, 2l+1} as one u32.

__global__ __launch_bounds__(256) void k_agg40(
    const u16* __restrict__ t, const int* __restrict__ roff,
    const int* __restrict__ col, const float* __restrict__ wsrc,
    const float* __restrict__ dinv, const float* __restrict__ bias,
    float* __restrict__ out, int n)
{
    int i = blockIdx.x * 8 + (threadIdx.x >> 5);
    if (i >= n) return;
    int l = threadIdx.x & 31;
    bool act = l < 20;
    int beg = roff[i], end = roff[i + 1];
    float di = dinv[i];

    float ax = 0.f, ay = 0.f;
    if (act) {
        u32 u = ((const u32*)(t + (size_t)i * NCLS))[l];
        ax = di * blo(u); ay = di * bhi(u);
    }
    int j = beg;
    for (; j + 7 < end; j += 8) {
        int s[8]; float w[8]; u32 u[8];
#pragma unroll
        for (int k = 0; k < 8; ++k) { s[k] = col[j + k]; w[k] = wsrc[j + k]; }
#pragma unroll
        for (int k = 0; k < 8; ++k)
            u[k] = act ? ((const u32*)(t + (size_t)s[k] * NCLS))[l] : 0u;
#pragma unroll
        for (int k = 0; k < 8; ++k) {
            ax = fmaf(w[k], blo(u[k]), ax);
            ay = fmaf(w[k], bhi(u[k]), ay);
        }
    }
    for (; j < end; ++j) {
        float w0 = wsrc[j];
        u32 u = act ? ((const u32*)(t + (size_t)col[j] * NCLS))[l] : 0u;
        ax = fmaf(w0, blo(u), ax);
        ay = fmaf(w0, bhi(u), ay);
    }

    float v0 = -INFINITY, v1 = -INFINITY;
    if (act) {
        float2 bb = ((const float2*)bias)[l];
        v0 = fmaf(di, ax, bb.x);
        v1 = fmaf(di, ay, bb.y);
    }
    float m = fmaxf(v0, v1);
#pragma unroll
    for (int d = 16; d > 0; d >>= 1) m = fmaxf(m, __shfl_xor(m, d, 32));
    float e = act ? (expf(v0 - m) + expf(v1 - m)) : 0.f;
    float ssum = e;
#pragma unroll
    for (int d = 16; d > 0; d >>= 1) ssum += __shfl_xor(ssum, d, 32);
    float ls = logf(ssum);
    if (act) {
        float2 o; o.x = v0 - m - ls; o.y = v1 - m - ls;
        ((float2*)(out + (size_t)i * NCLS))[l] = o;
    }
}

// ---------------- launch ----------------

extern "C" void kernel_launch(void* const* d_in, const int* in_sizes, int n_in,
                              void* d_out, int out_size, void* d_ws, size_t ws_size,
                              hipStream_t stream) {
    const float* features = (const float*)d_in[0];
    const int* edge_index = (const int*)d_in[1];
    const float* W1 = (const float*)d_in[2];
    const float* b1 = (const float*)d_in[3];
    const float* gamma1 = (const float*)d_in[4];
    const float* beta1 = (const float*)d_in[5];
    const float* W2 = (const float*)d_in[6];
    const float* b2 = (const float*)d_in[7];
    const float* gamma2 = (const float*)d_in[8];
    const float* beta2 = (const float*)d_in[9];
    const float* W3 = (const float*)d_in[10];
    const float* b3 = (const float*)d_in[11];
    float* out = (float*)d_out;

    int n = in_sizes[0] / FEAT;
    int E = in_sizes[1] / 2;

    char* p = (char*)d_ws;
    auto alloc = [&](size_t bytes) -> void* {
        void* r = (void*)p;
        p += (bytes + 255) & ~(size_t)255;
        return r;
    };
    int* cnt     = (int*)alloc((size_t)n * 4);
    int* row_off = (int*)alloc((size_t)(n + 1) * 4);
    int* cursor  = (int*)alloc((size_t)n * 4);
    int* colb    = (int*)alloc((size_t)E * 4);
    float* wsrc  = (float*)alloc((size_t)E * 4);
    int* bsum    = (int*)alloc(1024);
    int* boff    = (int*)alloc(1024);
    float* dinv  = (float*)alloc((size_t)n * 4);
    float* sums  = (float*)alloc(256 * 4);
    float* scale1 = (float*)alloc(128 * 4);
    float* shift1 = (float*)alloc(128 * 4);
    float* scale2 = (float*)alloc(128 * 4);
    float* shift2 = (float*)alloc(128 * 4);
    u16* hb      = (u16*)alloc((size_t)n * 128 * 2);   // transform output (bf16)
    u16* ab      = (u16*)alloc((size_t)n * 128 * 2);   // aggregated (bf16)

    const int* e_src = edge_index;
    const int* e_dst = edge_index + E;

    hipMemsetAsync(cnt, 0, (size_t)n * 4, stream);
    k_hist<<<(E + 255) / 256, 256, 0, stream>>>(e_dst, cnt, E);
    int nb = (n + 511) / 512;
    k_scan_a<<<nb, 256, 0, stream>>>(cnt, bsum, n);
    k_scan_b<<<1, 64, 0, stream>>>(bsum, boff, row_off, nb, n);
    k_scan_c<<<nb, 256, 0, stream>>>(cnt, boff, row_off, cursor, dinv, n);
    int nchunks = 160;   // 160 chunks x 8 partitions = 1280 blocks
    k_fill<<<nchunks * 8, 256, 0, stream>>>(e_src, e_dst, cursor, colb, E, n, nchunks);
    k_wsrc<<<(E + 255) / 256, 256, 0, stream>>>(colb, dinv, wsrc, E);

    int gb64 = (n + 63) / 64;
    int gb16 = (n + 15) / 16;
    int gb8 = (n + 7) / 8;

    // layer 1
    k_gemm128_f32<<<gb64, 256, 0, stream>>>(features, W1, hb, n);
    k_agg128<<<gb16, 256, 0, stream>>>(hb, row_off, colb, wsrc, dinv, b1, ab, n);
    hipMemsetAsync(sums, 0, 256 * 4, stream);
    k_bnstats<<<512, 256, 0, stream>>>(ab, sums, n);
    k_bnfinal<<<1, 128, 0, stream>>>(sums, gamma1, beta1, scale1, shift1, n);

    // layer 2 (BN1+ReLU fused into GEMM2 input staging)
    k_gemm128_bf16<<<gb64, 256, 0, stream>>>(ab, W2, scale1, shift1, hb, n);
    k_agg128<<<gb16, 256, 0, stream>>>(hb, row_off, colb, wsrc, dinv, b2, ab, n);
    hipMemsetAsync(sums, 0, 256 * 4, stream);
    k_bnstats<<<512, 256, 0, stream>>>(ab, sums, n);
    k_bnfinal<<<1, 128, 0, stream>>>(sums, gamma2, beta2, scale2, shift2, n);

    // layer 3: transform first, then 40-wide agg + log_softmax
    k_gemm40<<<(n + 255) / 256, 256, 0, stream>>>(ab, W3, scale2, shift2, hb, n);
    k_agg40<<<gb8, 256, 0, stream>>>(hb, row_off, colb, wsrc, dinv, b3, out, n);
}

// Round 7
// 385.919 us; speedup vs baseline: 1.5306x; 1.0675x over previous
//
#include <hip/hip_runtime.h>
#include <math.h>

#define FEAT 128
#define NCLS 40
#define BN_EPS 1e-5f

typedef unsigned short u16;
typedef unsigned int u32;
typedef __attribute__((ext_vector_type(8))) short bf16x8;
typedef __attribute__((ext_vector_type(4))) float f32x4;

// bf16 helpers (RNE pack, exact unpack)
__device__ inline u32 f2b2(float a, float b) {
    u32 ua = __float_as_uint(a), ub = __float_as_uint(b);
    ua = (ua + 0x7fffu + ((ua >> 16) & 1u)) >> 16;
    ub = (ub + 0x7fffu + ((ub >> 16) & 1u)) >> 16;
    return ua | (ub << 16);
}
__device__ inline u16 f2b1(float a) {
    u32 ua = __float_as_uint(a);
    return (u16)((ua + 0x7fffu + ((ua >> 16) & 1u)) >> 16);
}
__device__ inline float b2f(u16 u) { return __uint_as_float((u32)u << 16); }
__device__ inline float4 b4fv(ushort4 u) {
    return make_float4(b2f(u.x), b2f(u.y), b2f(u.z), b2f(u.w));
}
__device__ inline float blo(u32 u) { return __uint_as_float(u << 16); }
__device__ inline float bhi(u32 u) { return __uint_as_float(u & 0xffff0000u); }

// accumulate 8 bf16 (uint4) * w into a[0..7]
__device__ inline void b8acc(uint4 u, float w, float* a) {
    a[0] = fmaf(w, blo(u.x), a[0]); a[1] = fmaf(w, bhi(u.x), a[1]);
    a[2] = fmaf(w, blo(u.y), a[2]); a[3] = fmaf(w, bhi(u.y), a[3]);
    a[4] = fmaf(w, blo(u.z), a[4]); a[5] = fmaf(w, bhi(u.z), a[5]);
    a[6] = fmaf(w, blo(u.w), a[6]); a[7] = fmaf(w, bhi(u.w), a[7]);
}

// ---------------- graph prep ----------------

__global__ void k_hist(const int* __restrict__ dst, int* __restrict__ cnt, int E) {
    int e = blockIdx.x * 256 + threadIdx.x;
    if (e < E) atomicAdd(&cnt[dst[e]], 1);
}

__global__ void k_scan_a(const int* __restrict__ cnt, int* __restrict__ bsum, int n) {
    int t = threadIdx.x;
    int idx = blockIdx.x * 512 + t * 2;
    int v = 0;
    if (idx < n) v += cnt[idx];
    if (idx + 1 < n) v += cnt[idx + 1];
    for (int d = 1; d < 64; d <<= 1) v += __shfl_xor(v, d, 64);
    __shared__ int ws[4];
    int lane = t & 63, w = t >> 6;
    if (lane == 0) ws[w] = v;
    __syncthreads();
    if (t == 0) bsum[blockIdx.x] = ws[0] + ws[1] + ws[2] + ws[3];
}

__global__ void k_scan_b(const int* __restrict__ bsum, int* __restrict__ boff,
                         int* __restrict__ row_off, int nb, int n) {
    if (threadIdx.x == 0) {
        int run = 0;
        for (int i = 0; i < nb; ++i) { boff[i] = run; run += bsum[i]; }
        row_off[n] = run;
    }
}

__global__ void k_scan_c(const int* __restrict__ cnt, const int* __restrict__ boff,
                         int* __restrict__ row_off, int* __restrict__ cursor,
                         float* __restrict__ dinv, int n) {
    int t = threadIdx.x;
    int idx = blockIdx.x * 512 + t * 2;
    int v0 = (idx < n) ? cnt[idx] : 0;
    int v1 = (idx + 1 < n) ? cnt[idx + 1] : 0;
    int s = v0 + v1;
    int lane = t & 63, w = t >> 6;
    int incl = s;
    for (int d = 1; d < 64; d <<= 1) {
        int o = __shfl_up(incl, d, 64);
        if (lane >= d) incl += o;
    }
    __shared__ int wsum[4];
    if (lane == 63) wsum[w] = incl;
    __syncthreads();
    int wpre = 0;
    for (int i = 0; i < w; ++i) wpre += wsum[i];
    int base = boff[blockIdx.x] + wpre + incl - s;
    if (idx < n) {
        row_off[idx] = base; cursor[idx] = base;
        dinv[idx] = rsqrtf((float)(v0 + 1));
    }
    if (idx + 1 < n) {
        row_off[idx + 1] = base + v0; cursor[idx + 1] = base + v0;
        dinv[idx + 1] = rsqrtf((float)(v1 + 1));
    }
}

// XCD-partitioned CSR fill (see R5 notes: kills cross-XCD partial-line writeback)
__global__ __launch_bounds__(256) void k_fill(
    const int* __restrict__ src, const int* __restrict__ dst,
    int* __restrict__ cursor, int* __restrict__ col, int E, int n, int nchunks)
{
    int part = blockIdx.x & 7;
    int chunk = blockIdx.x >> 3;
    int lo = (int)(((long long)n * part) >> 3);
    int hi = (int)(((long long)n * (part + 1)) >> 3);
    int per = (E + nchunks - 1) / nchunks;
    int e0 = chunk * per;
    int e1 = e0 + per; if (e1 > E) e1 = E;
    for (int e = e0 + threadIdx.x; e < e1; e += 256) {
        int d = dst[e];
        if (d >= lo && d < hi) {
            int p = atomicAdd(&cursor[d], 1);
            col[p] = src[e];
        }
    }
}

__global__ void k_wsrc(const int* __restrict__ col, const float* __restrict__ dinv,
                       float* __restrict__ wsrc, int E) {
    int e = blockIdx.x * 256 + threadIdx.x;
    if (e < E) wsrc[e] = dinv[col[e]];
}

// ---------------- MFMA GEMM 128x128 ----------------
// Computes Y = X*W as D = (W^T)(X^T) per 16x16 MFMA tile so the C/D fragment
// (col=lane&15 -> node, row=quad*4+reg -> 4 consecutive feats) packs into one
// 8B store. A = W^T staged in LDS bf16 with XOR swizzle (k ^= (n&3)*32) so the
// 16-lane ds_read_b128 pattern covers all 32 banks (2-way max).
// Block: 256 thr = 4 waves; wave w -> nodes [blk*64 + w*16, +16); 8 n-tiles.

#define WT_PITCH 136

__device__ inline void stage_wt(const float* __restrict__ W, u16* Wt) {
    const float4* W4 = (const float4*)W;
#pragma unroll
    for (int i = 0; i < 16; ++i) {
        int li = threadIdx.x + i * 256;        // 4096 float4
        int k = li >> 5;
        int n0 = (li & 31) * 4;
        float4 w = W4[li];
        Wt[(n0 + 0) * WT_PITCH + ((k + ((n0 + 0 & 3) << 5)) & 127)] = f2b1(w.x);
        Wt[(n0 + 1) * WT_PITCH + ((k + ((n0 + 1 & 3) << 5)) & 127)] = f2b1(w.y);
        Wt[(n0 + 2) * WT_PITCH + ((k + ((n0 + 2 & 3) << 5)) & 127)] = f2b1(w.z);
        Wt[(n0 + 3) * WT_PITCH + ((k + ((n0 + 3 & 3) << 5)) & 127)] = f2b1(w.w);
    }
}

__device__ inline void mfma_core(const u16* Wt, const bf16x8* bfrag,
                                 u16* __restrict__ Y, int node, int M, int nl, int quad) {
    f32x4 acc[8];
#pragma unroll
    for (int nt = 0; nt < 8; ++nt) acc[nt] = (f32x4){0.f, 0.f, 0.f, 0.f};

#pragma unroll
    for (int s = 0; s < 4; ++s) {
#pragma unroll
        for (int nt = 0; nt < 8; ++nt) {
            int nrow = nt * 16 + nl;
            int kk = ((s * 32 + quad * 8) + ((nl & 3) << 5)) & 127;
            uint4 aw = *(const uint4*)&Wt[nrow * WT_PITCH + kk];
            bf16x8 af = *(bf16x8*)&aw;
            acc[nt] = __builtin_amdgcn_mfma_f32_16x16x32_bf16(af, bfrag[s], acc[nt], 0, 0, 0);
        }
    }
    if (node < M) {
#pragma unroll
        for (int nt = 0; nt < 8; ++nt) {
            uint2 o;
            o.x = f2b2(acc[nt][0], acc[nt][1]);
            o.y = f2b2(acc[nt][2], acc[nt][3]);
            *(uint2*)&Y[(size_t)node * 128 + nt * 16 + quad * 4] = o;
        }
    }
}

// layer 1: X fp32, no BN
__global__ __launch_bounds__(256) void k_mfma_l1(
    const float* __restrict__ X, const float* __restrict__ W,
    u16* __restrict__ Y, int M)
{
    __shared__ u16 Wt[128 * WT_PITCH];
    stage_wt(W, Wt);
    __syncthreads();

    int wv = threadIdx.x >> 6;
    int lane = threadIdx.x & 63;
    int nl = lane & 15, quad = lane >> 4;
    int node = blockIdx.x * 64 + wv * 16 + nl;

    bf16x8 bfrag[4];
    if (node < M) {
        const float4* xr = (const float4*)(X + (size_t)node * 128);
#pragma unroll
        for (int s = 0; s < 4; ++s) {
            float4 xa = xr[s * 8 + quad * 2];
            float4 xb = xr[s * 8 + quad * 2 + 1];
            uint4 bu;
            bu.x = f2b2(xa.x, xa.y); bu.y = f2b2(xa.z, xa.w);
            bu.z = f2b2(xb.x, xb.y); bu.w = f2b2(xb.z, xb.w);
            bfrag[s] = *(bf16x8*)&bu;
        }
    } else {
        uint4 z = make_uint4(0, 0, 0, 0);
#pragma unroll
        for (int s = 0; s < 4; ++s) bfrag[s] = *(bf16x8*)&z;
    }
    mfma_core(Wt, bfrag, Y, node, M, nl, quad);
}

// layer 2: X bf16 + fused BN+ReLU on input
__global__ __launch_bounds__(256) void k_mfma_l2(
    const u16* __restrict__ X, const float* __restrict__ W,
    const float* __restrict__ scale, const float* __restrict__ shift,
    u16* __restrict__ Y, int M)
{
    __shared__ u16 Wt[128 * WT_PITCH];
    stage_wt(W, Wt);
    __syncthreads();

    int wv = threadIdx.x >> 6;
    int lane = threadIdx.x & 63;
    int nl = lane & 15, quad = lane >> 4;
    int node = blockIdx.x * 64 + wv * 16 + nl;

    bf16x8 bfrag[4];
    if (node < M) {
        const uint4* xr = (const uint4*)(X + (size_t)node * 128);
#pragma unroll
        for (int s = 0; s < 4; ++s) {
            int k0 = s * 32 + quad * 8;
            uint4 xu = xr[s * 4 + quad];
            float4 sc0 = *(const float4*)(scale + k0);
            float4 sc1 = *(const float4*)(scale + k0 + 4);
            float4 sh0 = *(const float4*)(shift + k0);
            float4 sh1 = *(const float4*)(shift + k0 + 4);
            float v0 = fmaxf(fmaf(blo(xu.x), sc0.x, sh0.x), 0.f);
            float v1 = fmaxf(fmaf(bhi(xu.x), sc0.y, sh0.y), 0.f);
            float v2 = fmaxf(fmaf(blo(xu.y), sc0.z, sh0.z), 0.f);
            float v3 = fmaxf(fmaf(bhi(xu.y), sc0.w, sh0.w), 0.f);
            float v4 = fmaxf(fmaf(blo(xu.z), sc1.x, sh1.x), 0.f);
            float v5 = fmaxf(fmaf(bhi(xu.z), sc1.y, sh1.y), 0.f);
            float v6 = fmaxf(fmaf(blo(xu.w), sc1.z, sh1.z), 0.f);
            float v7 = fmaxf(fmaf(bhi(xu.w), sc1.w, sh1.w), 0.f);
            uint4 bu;
            bu.x = f2b2(v0, v1); bu.y = f2b2(v2, v3);
            bu.z = f2b2(v4, v5); bu.w = f2b2(v6, v7);
            bfrag[s] = *(bf16x8*)&bu;
        }
    } else {
        uint4 z = make_uint4(0, 0, 0, 0);
#pragma unroll
        for (int s = 0; s < 4; ++s) bfrag[s] = *(bf16x8*)&z;
    }
    mfma_core(Wt, bfrag, Y, node, M, nl, quad);
}

// ---------------- GEMM 128->40, bf16 X + fused BN+ReLU, bf16 out ----------------

__global__ __launch_bounds__(256) void k_gemm40(
    const u16* __restrict__ X, const float* __restrict__ W,
    const float* __restrict__ scale, const float* __restrict__ shift,
    u16* __restrict__ Y, int M)
{
    __shared__ float Ws[128 * 40];
    __shared__ float Xs[32 * 260];

    int t = threadIdx.x;
    int row0 = blockIdx.x * 256;
    int tx = t & 3, ty = t >> 2;

    {
        const float4* W4 = (const float4*)W;
        float4* Ws4 = (float4*)Ws;
#pragma unroll
        for (int i = 0; i < 5; ++i) Ws4[t + i * 256] = W4[t + i * 256];
    }

    float acc[4][10];
#pragma unroll
    for (int r = 0; r < 4; ++r)
#pragma unroll
        for (int c = 0; c < 10; ++c) acc[r][c] = 0.f;

    for (int k0 = 0; k0 < 128; k0 += 32) {
        __syncthreads();
        {
            int rr = t >> 3;
            int kc = (t & 7) * 4;
            float4 sc = *(const float4*)(scale + k0 + kc);
            float4 sh = *(const float4*)(shift + k0 + kc);
#pragma unroll
            for (int p = 0; p < 8; ++p) {
                int r = rr + p * 32;
                int grow = row0 + r;
                float4 v = make_float4(0.f, 0.f, 0.f, 0.f);
                if (grow < M) v = b4fv(*(const ushort4*)(X + (size_t)grow * 128 + k0 + kc));
                v.x = fmaxf(fmaf(v.x, sc.x, sh.x), 0.f);
                v.y = fmaxf(fmaf(v.y, sc.y, sh.y), 0.f);
                v.z = fmaxf(fmaf(v.z, sc.z, sh.z), 0.f);
                v.w = fmaxf(fmaf(v.w, sc.w, sh.w), 0.f);
                Xs[(kc + 0) * 260 + r] = v.x;
                Xs[(kc + 1) * 260 + r] = v.y;
                Xs[(kc + 2) * 260 + r] = v.z;
                Xs[(kc + 3) * 260 + r] = v.w;
            }
        }
        __syncthreads();
#pragma unroll 8
        for (int kk = 0; kk < 32; ++kk) {
            const float4 xv = *(const float4*)&Xs[kk * 260 + ty * 4];
            const float xr[4] = {xv.x, xv.y, xv.z, xv.w};
            float wc[10];
#pragma unroll
            for (int c = 0; c < 5; ++c) {
                float2 w2 = *(const float2*)&Ws[(k0 + kk) * 40 + tx * 10 + c * 2];
                wc[c * 2] = w2.x; wc[c * 2 + 1] = w2.y;
            }
#pragma unroll
            for (int r = 0; r < 4; ++r)
#pragma unroll
                for (int c = 0; c < 10; ++c)
                    acc[r][c] = fmaf(xr[r], wc[c], acc[r][c]);
        }
    }

#pragma unroll
    for (int r = 0; r < 4; ++r) {
        int grow = row0 + ty * 4 + r;
        if (grow < M) {
            u32* yp = (u32*)(Y + (size_t)grow * 40 + tx * 10);
#pragma unroll
            for (int c = 0; c < 5; ++c)
                yp[c] = f2b2(acc[r][c * 2], acc[r][c * 2 + 1]);
        }
    }
}

// ---------------- aggregation 128-wide (bf16 src, fp32 accum, bf16 out) ----------------

__global__ __launch_bounds__(256) void k_agg128(
    const u16* __restrict__ t, const int* __restrict__ roff,
    const int* __restrict__ col, const float* __restrict__ wsrc,
    const float* __restrict__ dinv, const float* __restrict__ bias,
    u16* __restrict__ out, int n)
{
    int wid = threadIdx.x >> 4;
    int lane = threadIdx.x & 15;
    int i = blockIdx.x * 16 + wid;
    if (i >= n) return;
    int beg = roff[i], end = roff[i + 1];
    float di = dinv[i];

    float a[8];
    {
        uint4 su = ((const uint4*)(t + (size_t)i * 128))[lane];
        a[0] = di * blo(su.x); a[1] = di * bhi(su.x);
        a[2] = di * blo(su.y); a[3] = di * bhi(su.y);
        a[4] = di * blo(su.z); a[5] = di * bhi(su.z);
        a[6] = di * blo(su.w); a[7] = di * bhi(su.w);
    }

    int j = beg;
    for (; j + 7 < end; j += 8) {
        int s[8]; float w[8]; uint4 v[8];
#pragma unroll
        for (int k = 0; k < 8; ++k) { s[k] = col[j + k]; w[k] = wsrc[j + k]; }
#pragma unroll
        for (int k = 0; k < 8; ++k) v[k] = ((const uint4*)(t + (size_t)s[k] * 128))[lane];
#pragma unroll
        for (int k = 0; k < 8; ++k) b8acc(v[k], w[k], a);
    }
    for (; j < end; ++j) {
        float w0 = wsrc[j];
        uint4 v = ((const uint4*)(t + (size_t)col[j] * 128))[lane];
        b8acc(v, w0, a);
    }

    float4 bA = ((const float4*)bias)[lane * 2];
    float4 bB = ((const float4*)bias)[lane * 2 + 1];
    uint4 o;
    o.x = f2b2(fmaf(di, a[0], bA.x), fmaf(di, a[1], bA.y));
    o.y = f2b2(fmaf(di, a[2], bA.z), fmaf(di, a[3], bA.w));
    o.z = f2b2(fmaf(di, a[4], bB.x), fmaf(di, a[5], bB.y));
    o.w = f2b2(fmaf(di, a[6], bB.z), fmaf(di, a[7], bB.w));
    ((uint4*)(out + (size_t)i * 128))[lane] = o;
}

// ---------------- BN stats ----------------

__global__ __launch_bounds__(256) void k_bnstats(const u16* __restrict__ a,
                                                 float* __restrict__ sums, int n) {
    int lane = threadIdx.x & 15;
    int rt = threadIdx.x >> 4;
    float s[8], q[8];
#pragma unroll
    for (int k = 0; k < 8; ++k) { s[k] = 0.f; q[k] = 0.f; }

    for (int i = blockIdx.x * 16 + rt; i < n; i += gridDim.x * 16) {
        uint4 u = ((const uint4*)(a + (size_t)i * 128))[lane];
        float v[8] = {blo(u.x), bhi(u.x), blo(u.y), bhi(u.y),
                      blo(u.z), bhi(u.z), blo(u.w), bhi(u.w)};
#pragma unroll
        for (int k = 0; k < 8; ++k) { s[k] += v[k]; q[k] = fmaf(v[k], v[k], q[k]); }
    }

    __shared__ float red[16][128];
#pragma unroll
    for (int k = 0; k < 8; ++k) red[rt][lane * 8 + k] = s[k];
    __syncthreads();
    if (threadIdx.x < 128) {
        float v = 0.f;
#pragma unroll
        for (int w = 0; w < 16; ++w) v += red[w][threadIdx.x];
        atomicAdd(&sums[threadIdx.x], v);
    }
    __syncthreads();
#pragma unroll
    for (int k = 0; k < 8; ++k) red[rt][lane * 8 + k] = q[k];
    __syncthreads();
    if (threadIdx.x < 128) {
        float v = 0.f;
#pragma unroll
        for (int w = 0; w < 16; ++w) v += red[w][threadIdx.x];
        atomicAdd(&sums[128 + threadIdx.x], v);
    }
}

__global__ void k_bnfinal(const float* __restrict__ sums, const float* __restrict__ gamma,
                          const float* __restrict__ beta, float* __restrict__ scale,
                          float* __restrict__ shift, int n) {
    int f = threadIdx.x;
    float inv_n = 1.f / (float)n;
    float mu = sums[f] * inv_n;
    float var = sums[128 + f] * inv_n - mu * mu;
    float rs = rsqrtf(var + BN_EPS);
    float sc = gamma[f] * rs;
    scale[f] = sc;
    shift[f] = beta[f] - mu * sc;
}

// ---------------- final: 40-wide agg + bias + log_softmax ----------------
// 8 lanes/node; lanes 0..4 hold 8 classes each as uint4 (16B loads: 5 addrs/row
// instead of 20). Softmax via width-8 shuffles.

__global__ __launch_bounds__(256) void k_agg40(
    const u16* __restrict__ t, const int* __restrict__ roff,
    const int* __restrict__ col, const float* __restrict__ wsrc,
    const float* __restrict__ dinv, const float* __restrict__ bias,
    float* __restrict__ out, int n)
{
    int i = blockIdx.x * 32 + (threadIdx.x >> 3);
    if (i >= n) return;
    int l = threadIdx.x & 7;
    bool act = l < 5;
    int beg = roff[i], end = roff[i + 1];
    float di = dinv[i];

    float a[8] = {0.f, 0.f, 0.f, 0.f, 0.f, 0.f, 0.f, 0.f};
    if (act) {
        uint4 su = ((const uint4*)(t + (size_t)i * NCLS))[l];
        a[0] = di * blo(su.x); a[1] = di * bhi(su.x);
        a[2] = di * blo(su.y); a[3] = di * bhi(su.y);
        a[4] = di * blo(su.z); a[5] = di * bhi(su.z);
        a[6] = di * blo(su.w); a[7] = di * bhi(su.w);
    }
    int j = beg;
    for (; j + 7 < end; j += 8) {
        int s[8]; float w[8]; uint4 v[8];
#pragma unroll
        for (int k = 0; k < 8; ++k) { s[k] = col[j + k]; w[k] = wsrc[j + k]; }
#pragma unroll
        for (int k = 0; k < 8; ++k)
            v[k] = act ? ((const uint4*)(t + (size_t)s[k] * NCLS))[l]
                       : make_uint4(0, 0, 0, 0);
#pragma unroll
        for (int k = 0; k < 8; ++k) b8acc(v[k], w[k], a);
    }
    for (; j < end; ++j) {
        float w0 = wsrc[j];
        uint4 v = act ? ((const uint4*)(t + (size_t)col[j] * NCLS))[l]
                      : make_uint4(0, 0, 0, 0);
        b8acc(v, w0, a);
    }

    float v[8];
    float m = -INFINITY;
    if (act) {
        float4 b0 = *(const float4*)(bias + l * 8);
        float4 b1 = *(const float4*)(bias + l * 8 + 4);
        v[0] = fmaf(di, a[0], b0.x); v[1] = fmaf(di, a[1], b0.y);
        v[2] = fmaf(di, a[2], b0.z); v[3] = fmaf(di, a[3], b0.w);
        v[4] = fmaf(di, a[4], b1.x); v[5] = fmaf(di, a[5], b1.y);
        v[6] = fmaf(di, a[6], b1.z); v[7] = fmaf(di, a[7], b1.w);
#pragma unroll
        for (int k = 0; k < 8; ++k) m = fmaxf(m, v[k]);
    }
#pragma unroll
    for (int d = 1; d < 8; d <<= 1) m = fmaxf(m, __shfl_xor(m, d, 8));
    float es = 0.f;
    if (act) {
#pragma unroll
        for (int k = 0; k < 8; ++k) es += expf(v[k] - m);
    }
#pragma unroll
    for (int d = 1; d < 8; d <<= 1) es += __shfl_xor(es, d, 8);
    float ls = logf(es);
    if (act) {
        float4 o0, o1;
        o0.x = v[0] - m - ls; o0.y = v[1] - m - ls;
        o0.z = v[2] - m - ls; o0.w = v[3] - m - ls;
        o1.x = v[4] - m - ls; o1.y = v[5] - m - ls;
        o1.z = v[6] - m - ls; o1.w = v[7] - m - ls;
        *(float4*)(out + (size_t)i * NCLS + l * 8) = o0;
        *(float4*)(out + (size_t)i * NCLS + l * 8 + 4) = o1;
    }
}

// ---------------- launch ----------------

extern "C" void kernel_launch(void* const* d_in, const int* in_sizes, int n_in,
                              void* d_out, int out_size, void* d_ws, size_t ws_size,
                              hipStream_t stream) {
    const float* features = (const float*)d_in[0];
    const int* edge_index = (const int*)d_in[1];
    const float* W1 = (const float*)d_in[2];
    const float* b1 = (const float*)d_in[3];
    const float* gamma1 = (const float*)d_in[4];
    const float* beta1 = (const float*)d_in[5];
    const float* W2 = (const float*)d_in[6];
    const float* b2 = (const float*)d_in[7];
    const float* gamma2 = (const float*)d_in[8];
    const float* beta2 = (const float*)d_in[9];
    const float* W3 = (const float*)d_in[10];
    const float* b3 = (const float*)d_in[11];
    float* out = (float*)d_out;

    int n = in_sizes[0] / FEAT;
    int E = in_sizes[1] / 2;

    char* p = (char*)d_ws;
    auto alloc = [&](size_t bytes) -> void* {
        void* r = (void*)p;
        p += (bytes + 255) & ~(size_t)255;
        return r;
    };
    int* cnt     = (int*)alloc((size_t)n * 4);
    int* row_off = (int*)alloc((size_t)(n + 1) * 4);
    int* cursor  = (int*)alloc((size_t)n * 4);
    int* colb    = (int*)alloc((size_t)E * 4);
    float* wsrc  = (float*)alloc((size_t)E * 4);
    int* bsum    = (int*)alloc(1024);
    int* boff    = (int*)alloc(1024);
    float* dinv  = (float*)alloc((size_t)n * 4);
    float* sums  = (float*)alloc(256 * 4);
    float* scale1 = (float*)alloc(128 * 4);
    float* shift1 = (float*)alloc(128 * 4);
    float* scale2 = (float*)alloc(128 * 4);
    float* shift2 = (float*)alloc(128 * 4);
    u16* hb      = (u16*)alloc((size_t)n * 128 * 2);
    u16* ab      = (u16*)alloc((size_t)n * 128 * 2);

    const int* e_src = edge_index;
    const int* e_dst = edge_index + E;

    hipMemsetAsync(cnt, 0, (size_t)n * 4, stream);
    k_hist<<<(E + 255) / 256, 256, 0, stream>>>(e_dst, cnt, E);
    int nb = (n + 511) / 512;
    k_scan_a<<<nb, 256, 0, stream>>>(cnt, bsum, n);
    k_scan_b<<<1, 64, 0, stream>>>(bsum, boff, row_off, nb, n);
    k_scan_c<<<nb, 256, 0, stream>>>(cnt, boff, row_off, cursor, dinv, n);
    int nchunks = 160;
    k_fill<<<nchunks * 8, 256, 0, stream>>>(e_src, e_dst, cursor, colb, E, n, nchunks);
    k_wsrc<<<(E + 255) / 256, 256, 0, stream>>>(colb, dinv, wsrc, E);

    int gb64 = (n + 63) / 64;
    int gb16 = (n + 15) / 16;
    int gb32 = (n + 31) / 32;

    // layer 1 (MFMA)
    k_mfma_l1<<<gb64, 256, 0, stream>>>(features, W1, hb, n);
    k_agg128<<<gb16, 256, 0, stream>>>(hb, row_off, colb, wsrc, dinv, b1, ab, n);
    hipMemsetAsync(sums, 0, 256 * 4, stream);
    k_bnstats<<<512, 256, 0, stream>>>(ab, sums, n);
    k_bnfinal<<<1, 128, 0, stream>>>(sums, gamma1, beta1, scale1, shift1, n);

    // layer 2 (MFMA, BN1+ReLU fused into B-fragment load)
    k_mfma_l2<<<gb64, 256, 0, stream>>>(ab, W2, scale1, shift1, hb, n);
    k_agg128<<<gb16, 256, 0, stream>>>(hb, row_off, colb, wsrc, dinv, b2, ab, n);
    hipMemsetAsync(sums, 0, 256 * 4, stream);
    k_bnstats<<<512, 256, 0, stream>>>(ab, sums, n);
    k_bnfinal<<<1, 128, 0, stream>>>(sums, gamma2, beta2, scale2, shift2, n);

    // layer 3: transform first, then 40-wide agg + log_softmax
    k_gemm40<<<(n + 255) / 256, 256, 0, stream>>>(ab, W3, scale2, shift2, hb, n);
    k_agg40<<<gb32, 256, 0, stream>>>(hb, row_off, colb, wsrc, dinv, b3, out, n);
}

// Round 8
// 359.522 us; speedup vs baseline: 1.6429x; 1.0734x over previous
//
#include <hip/hip_runtime.h>
#include <math.h>

#define FEAT 128
#define NCLS 40
#define BN_EPS 1e-5f

typedef unsigned short u16;
typedef unsigned int u32;
typedef __attribute__((ext_vector_type(8))) short bf16x8;
typedef __attribute__((ext_vector_type(4))) float f32x4;

// bf16 helpers (RNE pack, exact unpack)
__device__ inline u32 f2b2(float a, float b) {
    u32 ua = __float_as_uint(a), ub = __float_as_uint(b);
    ua = (ua + 0x7fffu + ((ua >> 16) & 1u)) >> 16;
    ub = (ub + 0x7fffu + ((ub >> 16) & 1u)) >> 16;
    return ua | (ub << 16);
}
__device__ inline u16 f2b1(float a) {
    u32 ua = __float_as_uint(a);
    return (u16)((ua + 0x7fffu + ((ua >> 16) & 1u)) >> 16);
}
__device__ inline float b2f(u16 u) { return __uint_as_float((u32)u << 16); }
__device__ inline float4 b4fv(ushort4 u) {
    return make_float4(b2f(u.x), b2f(u.y), b2f(u.z), b2f(u.w));
}
__device__ inline float blo(u32 u) { return __uint_as_float(u << 16); }
__device__ inline float bhi(u32 u) { return __uint_as_float(u & 0xffff0000u); }

__device__ inline void b8acc(uint4 u, float w, float* a) {
    a[0] = fmaf(w, blo(u.x), a[0]); a[1] = fmaf(w, bhi(u.x), a[1]);
    a[2] = fmaf(w, blo(u.y), a[2]); a[3] = fmaf(w, bhi(u.y), a[3]);
    a[4] = fmaf(w, blo(u.z), a[4]); a[5] = fmaf(w, bhi(u.z), a[5]);
    a[6] = fmaf(w, blo(u.w), a[6]); a[7] = fmaf(w, bhi(u.w), a[7]);
}

#define WT_PITCH 136
#define SMEM_BYTES (128 * WT_PITCH * 2)   // 34816; also covers hist's 25 KB

// ---------------- MFMA GEMM helpers ----------------
// Y = X*W computed as D = (W^T)(X^T) per 16x16x32 MFMA tile.
// C/D fragment: col=lane&15 -> node, row=quad*4+reg -> 4 consecutive feats.
// A = W^T in LDS bf16, XOR swizzle (k += (n&3)*32 mod 128) -> <=2-way banks.

__device__ inline void stage_wt(const float* __restrict__ W, u16* Wt) {
    const float4* W4 = (const float4*)W;
#pragma unroll
    for (int i = 0; i < 16; ++i) {
        int li = threadIdx.x + i * 256;        // 4096 float4
        int k = li >> 5;
        int n0 = (li & 31) * 4;
        float4 w = W4[li];
        Wt[(n0 + 0) * WT_PITCH + ((k + ((n0 + 0 & 3) << 5)) & 127)] = f2b1(w.x);
        Wt[(n0 + 1) * WT_PITCH + ((k + ((n0 + 1 & 3) << 5)) & 127)] = f2b1(w.y);
        Wt[(n0 + 2) * WT_PITCH + ((k + ((n0 + 2 & 3) << 5)) & 127)] = f2b1(w.z);
        Wt[(n0 + 3) * WT_PITCH + ((k + ((n0 + 3 & 3) << 5)) & 127)] = f2b1(w.w);
    }
}

__device__ inline void mfma_core(const u16* Wt, const bf16x8* bfrag,
                                 u16* __restrict__ Y, int node, int M, int nl, int quad) {
    f32x4 acc[8];
#pragma unroll
    for (int nt = 0; nt < 8; ++nt) acc[nt] = (f32x4){0.f, 0.f, 0.f, 0.f};
#pragma unroll
    for (int s = 0; s < 4; ++s) {
#pragma unroll
        for (int nt = 0; nt < 8; ++nt) {
            int nrow = nt * 16 + nl;
            int kk = ((s * 32 + quad * 8) + ((nl & 3) << 5)) & 127;
            uint4 aw = *(const uint4*)&Wt[nrow * WT_PITCH + kk];
            bf16x8 af = *(bf16x8*)&aw;
            acc[nt] = __builtin_amdgcn_mfma_f32_16x16x32_bf16(af, bfrag[s], acc[nt], 0, 0, 0);
        }
    }
    if (node < M) {
#pragma unroll
        for (int nt = 0; nt < 8; ++nt) {
            uint2 o;
            o.x = f2b2(acc[nt][0], acc[nt][1]);
            o.y = f2b2(acc[nt][2], acc[nt][3]);
            *(uint2*)&Y[(size_t)node * 128 + nt * 16 + quad * 4] = o;
        }
    }
}

// ---------------- fused: layer-1 MFMA GEMM + LDS-privatized histogram ----------------
// blocks [0, gemmBlocks): GEMM (independent of graph);
// blocks [gemmBlocks, +512): histogram, 8 node-partitions x 64 edge-chunks,
// counts in LDS (25 KB tile), flush nonzero counters with global atomics.

__global__ __launch_bounds__(256) void k_l1_hist(
    const float* __restrict__ X, const float* __restrict__ W, u16* __restrict__ Y, int M,
    const int* __restrict__ dst, int* __restrict__ cnt, int E, int gemmBlocks)
{
    __shared__ __align__(16) char smem[SMEM_BYTES];

    if ((int)blockIdx.x < gemmBlocks) {
        u16* Wt = (u16*)smem;
        stage_wt(W, Wt);
        __syncthreads();

        int wv = threadIdx.x >> 6;
        int lane = threadIdx.x & 63;
        int nl = lane & 15, quad = lane >> 4;
        int node = blockIdx.x * 64 + wv * 16 + nl;

        bf16x8 bfrag[4];
        if (node < M) {
            const float4* xr = (const float4*)(X + (size_t)node * 128);
#pragma unroll
            for (int s = 0; s < 4; ++s) {
                float4 xa = xr[s * 8 + quad * 2];
                float4 xb = xr[s * 8 + quad * 2 + 1];
                uint4 bu;
                bu.x = f2b2(xa.x, xa.y); bu.y = f2b2(xa.z, xa.w);
                bu.z = f2b2(xb.x, xb.y); bu.w = f2b2(xb.z, xb.w);
                bfrag[s] = *(bf16x8*)&bu;
            }
        } else {
            uint4 z = make_uint4(0, 0, 0, 0);
#pragma unroll
            for (int s = 0; s < 4; ++s) bfrag[s] = *(bf16x8*)&z;
        }
        mfma_core(Wt, bfrag, Y, node, M, nl, quad);
    } else {
        int* lc = (int*)smem;
        int hb = blockIdx.x - gemmBlocks;
        int part = hb & 7;
        int chunk = hb >> 3;               // 64 chunks
        int lo = (int)(((long long)M * part) >> 3);
        int hi = (int)(((long long)M * (part + 1)) >> 3);
        int range = hi - lo;
        for (int i = threadIdx.x; i < range; i += 256) lc[i] = 0;
        __syncthreads();
        int per = (E + 63) / 64;
        int e0 = chunk * per;
        int e1 = e0 + per; if (e1 > E) e1 = E;
        for (int e = e0 + threadIdx.x; e < e1; e += 256) {
            int d = dst[e];
            if (d >= lo && d < hi) atomicAdd(&lc[d - lo], 1);
        }
        __syncthreads();
        for (int i = threadIdx.x; i < range; i += 256) {
            int v = lc[i];
            if (v) atomicAdd(&cnt[lo + i], v);
        }
    }
}

// ---------------- scans ----------------

__global__ void k_scan_a(const int* __restrict__ cnt, int* __restrict__ bsum, int n) {
    int t = threadIdx.x;
    int idx = blockIdx.x * 512 + t * 2;
    int v = 0;
    if (idx < n) v += cnt[idx];
    if (idx + 1 < n) v += cnt[idx + 1];
    for (int d = 1; d < 64; d <<= 1) v += __shfl_xor(v, d, 64);
    __shared__ int ws[4];
    int lane = t & 63, w = t >> 6;
    if (lane == 0) ws[w] = v;
    __syncthreads();
    if (t == 0) bsum[blockIdx.x] = ws[0] + ws[1] + ws[2] + ws[3];
}

__global__ void k_scan_b(const int* __restrict__ bsum, int* __restrict__ boff,
                         int* __restrict__ row_off, int nb, int n) {
    if (threadIdx.x == 0) {
        int run = 0;
        for (int i = 0; i < nb; ++i) { boff[i] = run; run += bsum[i]; }
        row_off[n] = run;
    }
}

__global__ void k_scan_c(const int* __restrict__ cnt, const int* __restrict__ boff,
                         int* __restrict__ row_off, int* __restrict__ cursor,
                         float* __restrict__ dinv, int n) {
    int t = threadIdx.x;
    int idx = blockIdx.x * 512 + t * 2;
    int v0 = (idx < n) ? cnt[idx] : 0;
    int v1 = (idx + 1 < n) ? cnt[idx + 1] : 0;
    int s = v0 + v1;
    int lane = t & 63, w = t >> 6;
    int incl = s;
    for (int d = 1; d < 64; d <<= 1) {
        int o = __shfl_up(incl, d, 64);
        if (lane >= d) incl += o;
    }
    __shared__ int wsum[4];
    if (lane == 63) wsum[w] = incl;
    __syncthreads();
    int wpre = 0;
    for (int i = 0; i < w; ++i) wpre += wsum[i];
    int base = boff[blockIdx.x] + wpre + incl - s;
    if (idx < n) {
        row_off[idx] = base; cursor[idx] = base;
        dinv[idx] = rsqrtf((float)(v0 + 1));
    }
    if (idx + 1 < n) {
        row_off[idx + 1] = base + v0; cursor[idx + 1] = base + v0;
        dinv[idx + 1] = rsqrtf((float)(v1 + 1));
    }
}

// XCD-partitioned CSR fill + per-edge weight (wsrc scatter is XCD-local now)
__global__ __launch_bounds__(256) void k_fill(
    const int* __restrict__ src, const int* __restrict__ dst,
    int* __restrict__ cursor, int* __restrict__ col, float* __restrict__ wsrc,
    const float* __restrict__ dinv, int E, int n, int nchunks)
{
    int part = blockIdx.x & 7;
    int chunk = blockIdx.x >> 3;
    int lo = (int)(((long long)n * part) >> 3);
    int hi = (int)(((long long)n * (part + 1)) >> 3);
    int per = (E + nchunks - 1) / nchunks;
    int e0 = chunk * per;
    int e1 = e0 + per; if (e1 > E) e1 = E;
    for (int e = e0 + threadIdx.x; e < e1; e += 256) {
        int d = dst[e];
        if (d >= lo && d < hi) {
            int s = src[e];
            int p = atomicAdd(&cursor[d], 1);
            col[p] = s;
            wsrc[p] = dinv[s];
        }
    }
}

// ---------------- layer-2 MFMA GEMM, fused BN-final + BN+ReLU on input ----------------

__global__ __launch_bounds__(256) void k_mfma_l2(
    const u16* __restrict__ X, const float* __restrict__ W,
    const float* __restrict__ sums, const float* __restrict__ gamma,
    const float* __restrict__ beta, u16* __restrict__ Y, int M)
{
    __shared__ __align__(16) u16 Wt[128 * WT_PITCH];
    __shared__ __align__(16) float scs[128], shs[128];

    if (threadIdx.x < 128) {
        int f = threadIdx.x;
        float inv_n = 1.f / (float)M;
        float mu = sums[f] * inv_n;
        float var = sums[128 + f] * inv_n - mu * mu;
        float rs = rsqrtf(var + BN_EPS);
        float sc = gamma[f] * rs;
        scs[f] = sc;
        shs[f] = beta[f] - mu * sc;
    }
    stage_wt(W, Wt);
    __syncthreads();

    int wv = threadIdx.x >> 6;
    int lane = threadIdx.x & 63;
    int nl = lane & 15, quad = lane >> 4;
    int node = blockIdx.x * 64 + wv * 16 + nl;

    bf16x8 bfrag[4];
    if (node < M) {
        const uint4* xr = (const uint4*)(X + (size_t)node * 128);
#pragma unroll
        for (int s = 0; s < 4; ++s) {
            int k0 = s * 32 + quad * 8;
            uint4 xu = xr[s * 4 + quad];
            float4 sc0 = *(const float4*)&scs[k0];
            float4 sc1 = *(const float4*)&scs[k0 + 4];
            float4 sh0 = *(const float4*)&shs[k0];
            float4 sh1 = *(const float4*)&shs[k0 + 4];
            float v0 = fmaxf(fmaf(blo(xu.x), sc0.x, sh0.x), 0.f);
            float v1 = fmaxf(fmaf(bhi(xu.x), sc0.y, sh0.y), 0.f);
            float v2 = fmaxf(fmaf(blo(xu.y), sc0.z, sh0.z), 0.f);
            float v3 = fmaxf(fmaf(bhi(xu.y), sc0.w, sh0.w), 0.f);
            float v4 = fmaxf(fmaf(blo(xu.z), sc1.x, sh1.x), 0.f);
            float v5 = fmaxf(fmaf(bhi(xu.z), sc1.y, sh1.y), 0.f);
            float v6 = fmaxf(fmaf(blo(xu.w), sc1.z, sh1.z), 0.f);
            float v7 = fmaxf(fmaf(bhi(xu.w), sc1.w, sh1.w), 0.f);
            uint4 bu;
            bu.x = f2b2(v0, v1); bu.y = f2b2(v2, v3);
            bu.z = f2b2(v4, v5); bu.w = f2b2(v6, v7);
            bfrag[s] = *(bf16x8*)&bu;
        }
    } else {
        uint4 z = make_uint4(0, 0, 0, 0);
#pragma unroll
        for (int s = 0; s < 4; ++s) bfrag[s] = *(bf16x8*)&z;
    }
    mfma_core(Wt, bfrag, Y, node, M, nl, quad);
}

// ---------------- GEMM 128->40, fused BN-final + BN+ReLU, bf16 out ----------------

__global__ __launch_bounds__(256) void k_gemm40(
    const u16* __restrict__ X, const float* __restrict__ W,
    const float* __restrict__ sums, const float* __restrict__ gamma,
    const float* __restrict__ beta, u16* __restrict__ Y, int M)
{
    __shared__ float Ws[128 * 40];
    __shared__ __align__(16) float scs[128], shs[128];
    __shared__ float Xs[32 * 260];

    int t = threadIdx.x;
    int row0 = blockIdx.x * 256;
    int tx = t & 3, ty = t >> 2;

    if (t < 128) {
        float inv_n = 1.f / (float)M;
        float mu = sums[t] * inv_n;
        float var = sums[128 + t] * inv_n - mu * mu;
        float rs = rsqrtf(var + BN_EPS);
        float sc = gamma[t] * rs;
        scs[t] = sc;
        shs[t] = beta[t] - mu * sc;
    }
    {
        const float4* W4 = (const float4*)W;
        float4* Ws4 = (float4*)Ws;
#pragma unroll
        for (int i = 0; i < 5; ++i) Ws4[t + i * 256] = W4[t + i * 256];
    }

    float acc[4][10];
#pragma unroll
    for (int r = 0; r < 4; ++r)
#pragma unroll
        for (int c = 0; c < 10; ++c) acc[r][c] = 0.f;

    for (int k0 = 0; k0 < 128; k0 += 32) {
        __syncthreads();
        {
            int rr = t >> 3;
            int kc = (t & 7) * 4;
            float4 sc = *(const float4*)&scs[k0 + kc];
            float4 sh = *(const float4*)&shs[k0 + kc];
#pragma unroll
            for (int p = 0; p < 8; ++p) {
                int r = rr + p * 32;
                int grow = row0 + r;
                float4 v = make_float4(0.f, 0.f, 0.f, 0.f);
                if (grow < M) v = b4fv(*(const ushort4*)(X + (size_t)grow * 128 + k0 + kc));
                v.x = fmaxf(fmaf(v.x, sc.x, sh.x), 0.f);
                v.y = fmaxf(fmaf(v.y, sc.y, sh.y), 0.f);
                v.z = fmaxf(fmaf(v.z, sc.z, sh.z), 0.f);
                v.w = fmaxf(fmaf(v.w, sc.w, sh.w), 0.f);
                Xs[(kc + 0) * 260 + r] = v.x;
                Xs[(kc + 1) * 260 + r] = v.y;
                Xs[(kc + 2) * 260 + r] = v.z;
                Xs[(kc + 3) * 260 + r] = v.w;
            }
        }
        __syncthreads();
#pragma unroll 8
        for (int kk = 0; kk < 32; ++kk) {
            const float4 xv = *(const float4*)&Xs[kk * 260 + ty * 4];
            const float xr[4] = {xv.x, xv.y, xv.z, xv.w};
            float wc[10];
#pragma unroll
            for (int c = 0; c < 5; ++c) {
                float2 w2 = *(const float2*)&Ws[(k0 + kk) * 40 + tx * 10 + c * 2];
                wc[c * 2] = w2.x; wc[c * 2 + 1] = w2.y;
            }
#pragma unroll
            for (int r = 0; r < 4; ++r)
#pragma unroll
                for (int c = 0; c < 10; ++c)
                    acc[r][c] = fmaf(xr[r], wc[c], acc[r][c]);
        }
    }

#pragma unroll
    for (int r = 0; r < 4; ++r) {
        int grow = row0 + ty * 4 + r;
        if (grow < M) {
            u32* yp = (u32*)(Y + (size_t)grow * 40 + tx * 10);
#pragma unroll
            for (int c = 0; c < 5; ++c)
                yp[c] = f2b2(acc[r][c * 2], acc[r][c * 2 + 1]);
        }
    }
}

// ---------------- aggregation 128-wide ----------------

__global__ __launch_bounds__(256) void k_agg128(
    const u16* __restrict__ t, const int* __restrict__ roff,
    const int* __restrict__ col, const float* __restrict__ wsrc,
    const float* __restrict__ dinv, const float* __restrict__ bias,
    u16* __restrict__ out, int n)
{
    int wid = threadIdx.x >> 4;
    int lane = threadIdx.x & 15;
    int i = blockIdx.x * 16 + wid;
    if (i >= n) return;
    int beg = roff[i], end = roff[i + 1];
    float di = dinv[i];

    float a[8];
    {
        uint4 su = ((const uint4*)(t + (size_t)i * 128))[lane];
        a[0] = di * blo(su.x); a[1] = di * bhi(su.x);
        a[2] = di * blo(su.y); a[3] = di * bhi(su.y);
        a[4] = di * blo(su.z); a[5] = di * bhi(su.z);
        a[6] = di * blo(su.w); a[7] = di * bhi(su.w);
    }

    int j = beg;
    for (; j + 7 < end; j += 8) {
        int s[8]; float w[8]; uint4 v[8];
#pragma unroll
        for (int k = 0; k < 8; ++k) { s[k] = col[j + k]; w[k] = wsrc[j + k]; }
#pragma unroll
        for (int k = 0; k < 8; ++k) v[k] = ((const uint4*)(t + (size_t)s[k] * 128))[lane];
#pragma unroll
        for (int k = 0; k < 8; ++k) b8acc(v[k], w[k], a);
    }
    for (; j < end; ++j) {
        float w0 = wsrc[j];
        uint4 v = ((const uint4*)(t + (size_t)col[j] * 128))[lane];
        b8acc(v, w0, a);
    }

    float4 bA = ((const float4*)bias)[lane * 2];
    float4 bB = ((const float4*)bias)[lane * 2 + 1];
    uint4 o;
    o.x = f2b2(fmaf(di, a[0], bA.x), fmaf(di, a[1], bA.y));
    o.y = f2b2(fmaf(di, a[2], bA.z), fmaf(di, a[3], bA.w));
    o.z = f2b2(fmaf(di, a[4], bB.x), fmaf(di, a[5], bB.y));
    o.w = f2b2(fmaf(di, a[6], bB.z), fmaf(di, a[7], bB.w));
    ((uint4*)(out + (size_t)i * 128))[lane] = o;
}

// ---------------- BN stats ----------------

__global__ __launch_bounds__(256) void k_bnstats(const u16* __restrict__ a,
                                                 float* __restrict__ sums, int n) {
    int lane = threadIdx.x & 15;
    int rt = threadIdx.x >> 4;
    float s[8], q[8];
#pragma unroll
    for (int k = 0; k < 8; ++k) { s[k] = 0.f; q[k] = 0.f; }

    for (int i = blockIdx.x * 16 + rt; i < n; i += gridDim.x * 16) {
        uint4 u = ((const uint4*)(a + (size_t)i * 128))[lane];
        float v[8] = {blo(u.x), bhi(u.x), blo(u.y), bhi(u.y),
                      blo(u.z), bhi(u.z), blo(u.w), bhi(u.w)};
#pragma unroll
        for (int k = 0; k < 8; ++k) { s[k] += v[k]; q[k] = fmaf(v[k], v[k], q[k]); }
    }

    __shared__ float red[16][128];
#pragma unroll
    for (int k = 0; k < 8; ++k) red[rt][lane * 8 + k] = s[k];
    __syncthreads();
    if (threadIdx.x < 128) {
        float v = 0.f;
#pragma unroll
        for (int w = 0; w < 16; ++w) v += red[w][threadIdx.x];
        atomicAdd(&sums[threadIdx.x], v);
    }
    __syncthreads();
#pragma unroll
    for (int k = 0; k < 8; ++k) red[rt][lane * 8 + k] = q[k];
    __syncthreads();
    if (threadIdx.x < 128) {
        float v = 0.f;
#pragma unroll
        for (int w = 0; w < 16; ++w) v += red[w][threadIdx.x];
        atomicAdd(&sums[128 + threadIdx.x], v);
    }
}

// ---------------- final: 40-wide agg + bias + log_softmax ----------------

__global__ __launch_bounds__(256) void k_agg40(
    const u16* __restrict__ t, const int* __restrict__ roff,
    const int* __restrict__ col, const float* __restrict__ wsrc,
    const float* __restrict__ dinv, const float* __restrict__ bias,
    float* __restrict__ out, int n)
{
    int i = blockIdx.x * 32 + (threadIdx.x >> 3);
    if (i >= n) return;
    int l = threadIdx.x & 7;
    bool act = l < 5;
    int beg = roff[i], end = roff[i + 1];
    float di = dinv[i];

    float a[8] = {0.f, 0.f, 0.f, 0.f, 0.f, 0.f, 0.f, 0.f};
    if (act) {
        uint4 su = ((const uint4*)(t + (size_t)i * NCLS))[l];
        a[0] = di * blo(su.x); a[1] = di * bhi(su.x);
        a[2] = di * blo(su.y); a[3] = di * bhi(su.y);
        a[4] = di * blo(su.z); a[5] = di * bhi(su.z);
        a[6] = di * blo(su.w); a[7] = di * bhi(su.w);
    }
    int j = beg;
    for (; j + 7 < end; j += 8) {
        int s[8]; float w[8]; uint4 v[8];
#pragma unroll
        for (int k = 0; k < 8; ++k) { s[k] = col[j + k]; w[k] = wsrc[j + k]; }
#pragma unroll
        for (int k = 0; k < 8; ++k)
            v[k] = act ? ((const uint4*)(t + (size_t)s[k] * NCLS))[l]
                       : make_uint4(0, 0, 0, 0);
#pragma unroll
        for (int k = 0; k < 8; ++k) b8acc(v[k], w[k], a);
    }
    for (; j < end; ++j) {
        float w0 = wsrc[j];
        uint4 v = act ? ((const uint4*)(t + (size_t)col[j] * NCLS))[l]
                      : make_uint4(0, 0, 0, 0);
        b8acc(v, w0, a);
    }

    float v[8];
    float m = -INFINITY;
    if (act) {
        float4 b0 = *(const float4*)(bias + l * 8);
        float4 b1 = *(const float4*)(bias + l * 8 + 4);
        v[0] = fmaf(di, a[0], b0.x); v[1] = fmaf(di, a[1], b0.y);
        v[2] = fmaf(di, a[2], b0.z); v[3] = fmaf(di, a[3], b0.w);
        v[4] = fmaf(di, a[4], b1.x); v[5] = fmaf(di, a[5], b1.y);
        v[6] = fmaf(di, a[6], b1.z); v[7] = fmaf(di, a[7], b1.w);
#pragma unroll
        for (int k = 0; k < 8; ++k) m = fmaxf(m, v[k]);
    }
#pragma unroll
    for (int d = 1; d < 8; d <<= 1) m = fmaxf(m, __shfl_xor(m, d, 8));
    float es = 0.f;
    if (act) {
#pragma unroll
        for (int k = 0; k < 8; ++k) es += expf(v[k] - m);
    }
#pragma unroll
    for (int d = 1; d < 8; d <<= 1) es += __shfl_xor(es, d, 8);
    float ls = logf(es);
    if (act) {
        float4 o0, o1;
        o0.x = v[0] - m - ls; o0.y = v[1] - m - ls;
        o0.z = v[2] - m - ls; o0.w = v[3] - m - ls;
        o1.x = v[4] - m - ls; o1.y = v[5] - m - ls;
        o1.z = v[6] - m - ls; o1.w = v[7] - m - ls;
        *(float4*)(out + (size_t)i * NCLS + l * 8) = o0;
        *(float4*)(out + (size_t)i * NCLS + l * 8 + 4) = o1;
    }
}

// ---------------- launch ----------------

extern "C" void kernel_launch(void* const* d_in, const int* in_sizes, int n_in,
                              void* d_out, int out_size, void* d_ws, size_t ws_size,
                              hipStream_t stream) {
    const float* features = (const float*)d_in[0];
    const int* edge_index = (const int*)d_in[1];
    const float* W1 = (const float*)d_in[2];
    const float* b1 = (const float*)d_in[3];
    const float* gamma1 = (const float*)d_in[4];
    const float* beta1 = (const float*)d_in[5];
    const float* W2 = (const float*)d_in[6];
    const float* b2 = (const float*)d_in[7];
    const float* gamma2 = (const float*)d_in[8];
    const float* beta2 = (const float*)d_in[9];
    const float* W3 = (const float*)d_in[10];
    const float* b3 = (const float*)d_in[11];
    float* out = (float*)d_out;

    int n = in_sizes[0] / FEAT;
    int E = in_sizes[1] / 2;

    char* p = (char*)d_ws;
    auto alloc = [&](size_t bytes) -> void* {
        void* r = (void*)p;
        p += (bytes + 255) & ~(size_t)255;
        return r;
    };
    int* cnt     = (int*)alloc((size_t)n * 4);
    int* row_off = (int*)alloc((size_t)(n + 1) * 4);
    int* cursor  = (int*)alloc((size_t)n * 4);
    int* colb    = (int*)alloc((size_t)E * 4);
    float* wsrc  = (float*)alloc((size_t)E * 4);
    int* bsum    = (int*)alloc(1024);
    int* boff    = (int*)alloc(1024);
    float* dinv  = (float*)alloc((size_t)n * 4);
    float* sums  = (float*)alloc(256 * 4);
    u16* hb      = (u16*)alloc((size_t)n * 128 * 2);
    u16* ab      = (u16*)alloc((size_t)n * 128 * 2);

    const int* e_src = edge_index;
    const int* e_dst = edge_index + E;

    int gb64 = (n + 63) / 64;
    int gb16 = (n + 15) / 16;
    int gb32 = (n + 31) / 32;
    int nb = (n + 511) / 512;

    hipMemsetAsync(cnt, 0, (size_t)n * 4, stream);
    // fused: layer-1 GEMM (independent) + LDS-privatized histogram
    k_l1_hist<<<gb64 + 512, 256, 0, stream>>>(features, W1, hb, n, e_dst, cnt, E, gb64);
    k_scan_a<<<nb, 256, 0, stream>>>(cnt, bsum, n);
    k_scan_b<<<1, 64, 0, stream>>>(bsum, boff, row_off, nb, n);
    k_scan_c<<<nb, 256, 0, stream>>>(cnt, boff, row_off, cursor, dinv, n);
    int nchunks = 160;
    k_fill<<<nchunks * 8, 256, 0, stream>>>(e_src, e_dst, cursor, colb, wsrc, dinv, E, n, nchunks);

    // layer 1 aggregation + BN1 stats
    k_agg128<<<gb16, 256, 0, stream>>>(hb, row_off, colb, wsrc, dinv, b1, ab, n);
    hipMemsetAsync(sums, 0, 256 * 4, stream);
    k_bnstats<<<512, 256, 0, stream>>>(ab, sums, n);

    // layer 2 (BN1-final + BN+ReLU fused into GEMM input)
    k_mfma_l2<<<gb64, 256, 0, stream>>>(ab, W2, sums, gamma1, beta1, hb, n);
    k_agg128<<<gb16, 256, 0, stream>>>(hb, row_off, colb, wsrc, dinv, b2, ab, n);
    hipMemsetAsync(sums, 0, 256 * 4, stream);
    k_bnstats<<<512, 256, 0, stream>>>(ab, sums, n);

    // layer 3: transform (BN2-final fused), then 40-wide agg + log_softmax
    k_gemm40<<<(n + 255) / 256, 256, 0, stream>>>(ab, W3, sums, gamma2, beta2, hb, n);
    k_agg40<<<gb32, 256, 0, stream>>>(hb, row_off, colb, wsrc, dinv, b3, out, n);
}